// Round 2
// baseline (360.109 us; speedup 1.0000x reference)
//
#include <hip/hip_runtime.h>
#include <hip/hip_bf16.h>
#include <math.h>

#define B_   4
#define N_   2048
#define D_   512
#define H_   8
#define DH_  64
#define C_   3
#define HID_ 1365
#define HIDP 1408          // padded HID (11 * 128)
#define ROWS_ (B_*N_)      // 8192
#define TD_  (3*D_)        // 1536

typedef __attribute__((ext_vector_type(8))) short short8;   // 8 bf16 = 4 VGPR
typedef __attribute__((ext_vector_type(4))) float floatx4;
typedef __attribute__((ext_vector_type(2))) unsigned uint2v;

#define MFMA16(a,b,c) __builtin_amdgcn_mfma_f32_16x16x32_bf16(a,b,c,0,0,0)

typedef __attribute__((address_space(3))) unsigned lds_u32;
typedef __attribute__((address_space(1))) unsigned glb_u32;

__device__ __forceinline__ short sh(float v){
  union { __hip_bfloat16 b; short s; } u;
  u.b = __float2bfloat16(v);
  return u.s;
}

// pack two floats into one u32 of 2 bf16 (low = a); compiler fuses to cvt_pk
__device__ __forceinline__ unsigned pk2(float a, float b){
  union { short s[2]; unsigned u; } z;
  z.s[0] = sh(a); z.s[1] = sh(b);
  return z.u;
}

// global-layout segment swizzle: within each 64-short k-block, 16B segment s -> s ^ (row&7)
__device__ __forceinline__ int swz(int col, int row){
  return (col & ~63) | (col & 7) | ((((col >> 3) & 7) ^ (row & 7)) << 3);
}

// async global->LDS stage: ROWS rows of PITCH shorts (16B-swizzled global layout assumed).
template<int ROWS, int PITCH, int WAVES = 4>
__device__ __forceinline__ void stageG(short* __restrict__ lds,
    const short* __restrict__ g, int ldg, int t){
  const int LPR = PITCH/8;          // lanes per row
  const int RPI = 64/LPR;           // rows per instruction
  const int PW  = (ROWS/RPI)/WAVES; // instructions per wave
  int lane = t & 63, w = t >> 6;
  #pragma unroll
  for (int i = 0; i < PW; ++i){
    int r0  = (w*PW + i)*RPI;
    int row = r0 + lane/LPR;
    const short* ga = g + (size_t)row*ldg + (lane % LPR)*8;
    short* la = lds + r0*PITCH;     // wave-uniform; HW adds lane*16B
    __builtin_amdgcn_global_load_lds((const glb_u32*)ga, (lds_u32*)la, 16, 0, 0);
  }
}

// MFMA fragment from unpadded swizzled LDS tile
__device__ __forceinline__ short8 fragS(const short* __restrict__ lds, int pitch,
    int mbase, int lane, int kk){
  int row  = mbase + (lane & 15);
  int seg  = (kk >> 3) + (lane >> 4);
  int phys = seg ^ (row & 7);
  return *(const short8*)(lds + row*pitch + phys*8);
}

// ---------------- merged: weight transpose-convert (swizzled) + coord proj + LN1 ----------------
__global__ __launch_bounds__(256) void convT_all(
    const float* __restrict__ Wqkv, const float* __restrict__ Wo,
    const float* __restrict__ W1, const float* __restrict__ W2,
    const float* __restrict__ W3,
    short* __restrict__ Wtqkv, short* __restrict__ Wto,
    short* __restrict__ Wt1, short* __restrict__ Wt2, short* __restrict__ Wt3,
    const float* __restrict__ coords, const float* __restrict__ Wc,
    float* __restrict__ tv,
    const float* __restrict__ x, const float* __restrict__ ln1_w,
    const float* __restrict__ ln1_b, short* __restrict__ h){
  int id = blockIdx.x;
  int t = threadIdx.x;
  if (id >= 3392){            // ---- LN1 rows ----
    int row = id - 3392;
    size_t base = (size_t)row * D_;
    float v0 = x[base + t];
    float v1 = x[base + t + 256];
    float s  = v0 + v1;
    float s2 = v0*v0 + v1*v1;
    #pragma unroll
    for (int off = 32; off >= 1; off >>= 1){
      s  += __shfl_xor(s,  off, 64);
      s2 += __shfl_xor(s2, off, 64);
    }
    __shared__ float red[8];
    int lane = t & 63, wv = t >> 6;
    if (lane == 0){ red[wv] = s; red[4+wv] = s2; }
    __syncthreads();
    float sum  = red[0]+red[1]+red[2]+red[3];
    float sum2 = red[4]+red[5]+red[6]+red[7];
    float mean = sum * (1.0f/D_);
    float var  = sum2 * (1.0f/D_) - mean*mean;
    float inv  = rsqrtf(fmaxf(var, 0.f) + 1e-5f);
    h[base + swz(t,     row)] = sh((v0-mean)*inv*ln1_w[t]     + ln1_b[t]);
    h[base + swz(t+256, row)] = sh((v1-mean)*inv*ln1_w[t+256] + ln1_b[t+256]);
    return;
  }
  if (id >= 3136){            // ---- coord projection: tv = coords·Wc * log2(e) ----
    int idx = (id - 3136)*256 + t;
    int n = idx & (N_-1);
    int hh = (idx >> 11) & (H_-1);
    int b = idx >> 14;
    float s = 0.f;
    #pragma unroll
    for (int cc = 0; cc < C_; ++cc)
      s += coords[((size_t)(b*N_+n))*C_ + cc] * Wc[cc*H_ + hh];
    tv[idx] = s * 1.44269504f;       // pre-scaled into exp2 domain
    return;
  }
  // ---- weight transpose-convert ----
  __shared__ float tile[32][33];
  const float* in; short* out; int K, NN, Kp, nx;
  if (id < 768)      { in=Wqkv; out=Wtqkv; K=512;  NN=1536; Kp=512;  nx=48; }
  else if (id < 1024){ in=Wo;   out=Wto;   K=512;  NN=512;  Kp=512;  nx=16; id-=768; }
  else if (id < 1728){ in=W1;   out=Wt1;   K=512;  NN=HID_; Kp=512;  nx=44; id-=1024; }
  else if (id < 2432){ in=W2;   out=Wt2;   K=512;  NN=HID_; Kp=512;  nx=44; id-=1728; }
  else               { in=W3;   out=Wt3;   K=HID_; NN=512;  Kp=HIDP; nx=16; id-=2432; }
  int nt0 = (id % nx)*32, kt0 = (id / nx)*32;
  int r = t >> 5, cc = t & 31;
  #pragma unroll
  for (int i=0;i<4;++i){
    int k = kt0 + i*8 + r, n = nt0 + cc;
    tile[i*8+r][cc] = (k<K && n<NN) ? in[(size_t)k*NN + n] : 0.f;
  }
  __syncthreads();
  #pragma unroll
  for (int i=0;i<4;++i){
    int n = nt0 + i*8 + r, k = kt0 + cc;
    out[(size_t)n*Kp + swz(k, n)] = sh(tile[cc][i*8+r]);
  }
}

// ---------------- LayerNorm (f32 in, swizzled bf16 out) ----------------
__global__ __launch_bounds__(256) void ln_kernel(const float* __restrict__ x,
        const float* __restrict__ w, const float* __restrict__ b,
        short* __restrict__ out){
  int row = blockIdx.x;
  size_t base = (size_t)row * D_;
  int t = threadIdx.x;
  float v0 = x[base + t];
  float v1 = x[base + t + 256];
  float s  = v0 + v1;
  float s2 = v0*v0 + v1*v1;
  #pragma unroll
  for (int off = 32; off >= 1; off >>= 1){
    s  += __shfl_xor(s,  off, 64);
    s2 += __shfl_xor(s2, off, 64);
  }
  __shared__ float red[8];
  int lane = t & 63, wv = t >> 6;
  if (lane == 0){ red[wv] = s; red[4+wv] = s2; }
  __syncthreads();
  float sum  = red[0]+red[1]+red[2]+red[3];
  float sum2 = red[4]+red[5]+red[6]+red[7];
  float mean = sum * (1.0f/D_);
  float var  = sum2 * (1.0f/D_) - mean*mean;
  float inv  = rsqrtf(fmaxf(var, 0.f) + 1e-5f);
  out[base + swz(t,     row)] = sh((v0-mean)*inv*w[t]     + b[t]);
  out[base + swz(t+256, row)] = sh((v1-mean)*inv*w[t+256] + b[t+256]);
}

// ---------------- QKV GEMM 128x128 -> qb/kb [bh][n][hd] swz, vbt [bh][hd][n] swz ----------------
__global__ __launch_bounds__(256) void qkv_gemm(
    const short* __restrict__ A, const short* __restrict__ Bt,
    const float* __restrict__ bias,
    short* __restrict__ qb, short* __restrict__ kb, short* __restrict__ vbt){
  __shared__ short As[128*64];
  __shared__ short Bs[128*64];
  int t = threadIdx.x;
  int lane = t & 63, w = t >> 6;
  int wr = (w >> 1) * 64, wc = (w & 1) * 64;
  int col0 = blockIdx.x * 128, row0 = blockIdx.y * 128;
  floatx4 acc[4][4];
  #pragma unroll
  for (int mt=0;mt<4;++mt)
    #pragma unroll
    for (int nt=0;nt<4;++nt) acc[mt][nt] = (floatx4){0.f,0.f,0.f,0.f};
  for (int k0 = 0; k0 < D_; k0 += 64){
    __syncthreads();
    stageG<128,64>(As, A  + (size_t)row0*D_ + k0, D_, t);
    stageG<128,64>(Bs, Bt + (size_t)col0*D_ + k0, D_, t);
    __syncthreads();
    #pragma unroll
    for (int kk = 0; kk < 64; kk += 32){
      short8 af[4], bf[4];
      #pragma unroll
      for (int mt=0;mt<4;++mt) af[mt] = fragS(As, 64, wr+mt*16, lane, kk);
      #pragma unroll
      for (int nt=0;nt<4;++nt) bf[nt] = fragS(Bs, 64, wc+nt*16, lane, kk);
      #pragma unroll
      for (int mt=0;mt<4;++mt)
        #pragma unroll
        for (int nt=0;nt<4;++nt)
          acc[mt][nt] = MFMA16(af[mt], bf[nt], acc[mt][nt]);
    }
  }
  int quad = lane >> 4, c = lane & 15;
  #pragma unroll
  for (int mt=0;mt<4;++mt){
    #pragma unroll
    for (int nt=0;nt<4;++nt){
      #pragma unroll
      for (int r=0;r<4;++r){
        int row = row0 + wr + mt*16 + quad*4 + r;
        int col = col0 + wc + nt*16 + c;
        float v = acc[mt][nt][r] + bias[col];
        int bidx = row >> 11, n = row & (N_-1);
        int which = col >> 9, d = col & (D_-1), hh = d >> 6, hd = d & 63;
        short sv = sh(v);
        if (which == 0)
          qb[(((size_t)(bidx*H_ + hh))*N_ + n)*DH_ + swz(hd, n)] = sv;
        else if (which == 1)
          kb[(((size_t)(bidx*H_ + hh))*N_ + n)*DH_ + swz(hd, n)] = sv;
        else  // V transposed: [bh][hd][n], n swizzled by hd
          vbt[(((size_t)(bidx*H_ + hh))*DH_ + hd)*N_ + swz(n, hd)] = sv;
      }
    }
  }
}

// ---------------- MFMA GEMM 128x128 tile, BK=64, out = acc + bias + resid (f32) ----------------
__global__ __launch_bounds__(256) void gemm128(
    const short* __restrict__ A, int lda,
    const short* __restrict__ Bt, int Ktot,
    const float* __restrict__ bias,
    const float* __restrict__ resid, float* __restrict__ outF){
  __shared__ short As[128*64];
  __shared__ short Bs[128*64];
  int t = threadIdx.x, lane = t & 63, w = t >> 6;
  int wr = (w >> 1) * 64, wc = (w & 1) * 64;
  int col0 = blockIdx.x * 128, row0 = blockIdx.y * 128;
  floatx4 acc[4][4];
  #pragma unroll
  for (int mt=0;mt<4;++mt)
    #pragma unroll
    for (int nt=0;nt<4;++nt) acc[mt][nt] = (floatx4){0.f,0.f,0.f,0.f};
  for (int k0 = 0; k0 < Ktot; k0 += 64){
    __syncthreads();
    stageG<128,64>(As, A  + (size_t)row0*lda + k0, lda, t);
    stageG<128,64>(Bs, Bt + (size_t)col0*Ktot + k0, Ktot, t);
    __syncthreads();
    #pragma unroll
    for (int kk = 0; kk < 64; kk += 32){
      short8 af[4], bf[4];
      #pragma unroll
      for (int mt=0;mt<4;++mt) af[mt] = fragS(As, 64, wr+mt*16, lane, kk);
      #pragma unroll
      for (int nt=0;nt<4;++nt) bf[nt] = fragS(Bs, 64, wc+nt*16, lane, kk);
      #pragma unroll
      for (int mt=0;mt<4;++mt)
        #pragma unroll
        for (int nt=0;nt<4;++nt)
          acc[mt][nt] = MFMA16(af[mt], bf[nt], acc[mt][nt]);
    }
  }
  int quad = lane >> 4, c = lane & 15;
  #pragma unroll
  for (int mt=0;mt<4;++mt){
    #pragma unroll
    for (int nt=0;nt<4;++nt){
      #pragma unroll
      for (int r=0;r<4;++r){
        int row = row0 + wr + mt*16 + quad*4 + r;
        int col = col0 + wc + nt*16 + c;
        size_t idx = (size_t)row*D_ + col;
        outF[idx] = acc[mt][nt][r] + bias[col] + resid[idx];
      }
    }
  }
}

// ---------------- fused SwiGLU gate GEMM: 128x128 tile, dual-B, swizzled out ----------------
__global__ __launch_bounds__(256) void gate_gemm(
    const short* __restrict__ A,
    const short* __restrict__ Bt1, const short* __restrict__ Bt2,
    const float* __restrict__ b1, const float* __restrict__ b2,
    short* __restrict__ ff){
  __shared__ short As[128*64];
  __shared__ short B1s[128*64];
  __shared__ short B2s[128*64];
  int t = threadIdx.x, lane = t & 63, w = t >> 6;
  int wr = (w >> 1) * 64, wc = (w & 1) * 64;
  int col0 = blockIdx.x * 128, row0 = blockIdx.y * 128;
  floatx4 a1[4][4], a2[4][4];
  #pragma unroll
  for (int mt=0;mt<4;++mt)
    #pragma unroll
    for (int nt=0;nt<4;++nt){
      a1[mt][nt] = (floatx4){0.f,0.f,0.f,0.f};
      a2[mt][nt] = (floatx4){0.f,0.f,0.f,0.f};
    }
  for (int k0 = 0; k0 < D_; k0 += 64){
    __syncthreads();
    stageG<128,64>(As, A + (size_t)row0*D_ + k0, D_, t);
    stageG<128,64>(B1s, Bt1 + (size_t)col0*D_ + k0, D_, t);
    stageG<128,64>(B2s, Bt2 + (size_t)col0*D_ + k0, D_, t);
    __syncthreads();
    #pragma unroll
    for (int kk = 0; kk < 64; kk += 32){
      short8 af[4], f1[4], f2[4];
      #pragma unroll
      for (int mt=0;mt<4;++mt) af[mt] = fragS(As, 64, wr+mt*16, lane, kk);
      #pragma unroll
      for (int nt=0;nt<4;++nt){
        f1[nt] = fragS(B1s, 64, wc+nt*16, lane, kk);
        f2[nt] = fragS(B2s, 64, wc+nt*16, lane, kk);
      }
      #pragma unroll
      for (int mt=0;mt<4;++mt)
        #pragma unroll
        for (int nt=0;nt<4;++nt){
          a1[mt][nt] = MFMA16(af[mt], f1[nt], a1[mt][nt]);
          a2[mt][nt] = MFMA16(af[mt], f2[nt], a2[mt][nt]);
        }
    }
  }
  int quad = lane >> 4, c = lane & 15;
  #pragma unroll
  for (int mt=0;mt<4;++mt){
    #pragma unroll
    for (int nt=0;nt<4;++nt){
      #pragma unroll
      for (int r=0;r<4;++r){
        int row = row0 + wr + mt*16 + quad*4 + r;
        int col = col0 + wc + nt*16 + c;
        float g1 = a1[mt][nt][r] + (col < HID_ ? b1[col] : 0.f);
        float g2 = a2[mt][nt][r] + (col < HID_ ? b2[col] : 0.f);
        float sig = 1.f / (1.f + __expf(-g1));
        ff[(size_t)row*HIDP + swz(col, row)] = sh(g1*sig*g2);
      }
    }
  }
}

// ---------------- MFMA flash attention, swapped-QK^T, in-register softmax ----------------
// 512 threads = 8 waves: 4 q-groups (32 rows each) x 2 key-halves (64 keys each).
// 4 waves/SIMD for latency hiding; key-half partials (O,l) merged via LDS at end
// (fixed-max softmax -> partials merge by plain addition).
#define EXP2SC 0.18033688011112042f   // 0.125 * log2(e)
__global__ __launch_bounds__(512,4) void attn_mfma(
    const short* __restrict__ qb, const short* __restrict__ kbuf,
    const short* __restrict__ vbt, const float* __restrict__ tv,
    short* __restrict__ o){
  __shared__ short Ks2[2][128*64];        // [key][hd] swizzled
  __shared__ short Vt2[2][64*128];        // [hd][key] swizzled
  __shared__ __align__(16) float tsAll[2048];  // tv row (pre-scaled by log2e)
  int qt = blockIdx.x, h = blockIdx.y, b = blockIdx.z;
  int bh = b*H_ + h;
  int t = threadIdx.x, lane = t & 63, w = t >> 6;
  int qg = w & 3, kg = w >> 2;            // q-group, key-half
  int quad = lane >> 4, c = lane & 15;
  const short* Kbase = kbuf + (size_t)bh*N_*DH_;
  const short* Vbase = vbt  + (size_t)bh*DH_*N_;

  *(floatx4*)&tsAll[t*4] = *(const floatx4*)&tv[(size_t)bh*N_ + t*4];
  // stage Q into buffer 1; stage kt=0 K/V into buffer 0
  stageG<128,64,8>(Ks2[1], qb + ((size_t)bh*N_ + qt*128)*DH_, DH_, t);
  stageG<128,64,8>(Ks2[0], Kbase, DH_, t);
  stageG<64,128,8>(Vt2[0], Vbase, N_, t);
  __syncthreads();
  short8 qf[2][2];
  #pragma unroll
  for (int mt=0;mt<2;++mt)
    #pragma unroll
    for (int kh=0;kh<2;++kh)
      qf[mt][kh] = fragS(Ks2[1], 64, qg*32 + mt*16, lane, kh*32);
  floatx4 O[2][4];
  float l_i[2] = {0.f, 0.f};
  #pragma unroll
  for (int mt=0;mt<2;++mt)
    #pragma unroll
    for (int nt=0;nt<4;++nt) O[mt][nt] = (floatx4){0.f,0.f,0.f,0.f};
  __syncthreads();   // all waves finished reading Q before buffer 1 is restaged

  for (int kt = 0; kt < N_/128; ++kt){
    int cur = kt & 1;
    if (kt + 1 < N_/128){   // issue next-tile stage; overlaps this tile's compute
      stageG<128,64,8>(Ks2[cur^1], Kbase + (size_t)(kt+1)*128*DH_, DH_, t);
      stageG<64,128,8>(Vt2[cur^1], Vbase + (kt+1)*128, N_, t);
    }
    const short* Kc  = Ks2[cur];
    const short* Vc  = Vt2[cur];
    const float* tsc = tsAll + kt*128;
    #pragma unroll
    for (int kb = 0; kb < 2; ++kb){        // this wave's two 32-key blocks
      int kb4 = kg*2 + kb;
      floatx4 St[2][2];
      #pragma unroll
      for (int i=0;i<2;++i){
        St[i][0] = (floatx4){0.f,0.f,0.f,0.f};
        St[i][1] = (floatx4){0.f,0.f,0.f,0.f};
      }
      #pragma unroll
      for (int kh=0;kh<2;++kh){
        short8 kf0 = fragS(Kc, 64, kb4*32,      lane, kh*32);
        short8 kf1 = fragS(Kc, 64, kb4*32 + 16, lane, kh*32);
        #pragma unroll
        for (int mt=0;mt<2;++mt){
          St[0][mt] = MFMA16(kf0, qf[mt][kh], St[0][mt]);   // C[key][q]
          St[1][mt] = MFMA16(kf1, qf[mt][kh], St[1][mt]);
        }
      }
      floatx4 t0 = *(const floatx4*)&tsc[kb4*32 + quad*4];
      floatx4 t1 = *(const floatx4*)&tsc[kb4*32 + 16 + quad*4];
      short8 pbf[2];
      #pragma unroll
      for (int mt=0;mt<2;++mt){
        float p0[4], p1[4];
        #pragma unroll
        for (int r=0;r<4;++r){
          p0[r] = __builtin_amdgcn_exp2f(fmaf(St[0][mt][r], EXP2SC, -t0[r]));
          p1[r] = __builtin_amdgcn_exp2f(fmaf(St[1][mt][r], EXP2SC, -t1[r]));
        }
        l_i[mt] += (p0[0]+p0[1]) + (p0[2]+p0[3]) + (p1[0]+p1[1]) + (p1[2]+p1[3]);
        // pack consecutive-key pairs, then quad-regroup to the B-fragment layout
        unsigned X0 = pk2(p0[0], p0[1]), X1 = pk2(p0[2], p0[3]);
        unsigned Y0 = pk2(p1[0], p1[1]), Y1 = pk2(p1[2], p1[3]);
        auto u0 = __builtin_amdgcn_permlane32_swap(X0, Y0, false, false);
        auto v0 = __builtin_amdgcn_permlane16_swap(u0[0], u0[1], false, false);
        auto u1 = __builtin_amdgcn_permlane32_swap(X1, Y1, false, false);
        auto v1 = __builtin_amdgcn_permlane16_swap(u1[0], u1[1], false, false);
        union { short8 s; unsigned uu[4]; } pb;
        pb.uu[0] = v0[0]; pb.uu[1] = v1[0]; pb.uu[2] = v0[1]; pb.uu[3] = v1[1];
        pbf[mt] = pb.s;
      }
      // O^T += V^T · P^T   (C[d][q])
      #pragma unroll
      for (int nt=0;nt<4;++nt){
        short8 vf = fragS(Vc, 128, nt*16, lane, kb4*32);
        #pragma unroll
        for (int mt=0;mt<2;++mt)
          O[mt][nt] = MFMA16(vf, pbf[mt], O[mt][nt]);
      }
    }
    __syncthreads();
  }
  // ---- merge key-half partials via LDS overlays on dead K/V buffers ----
  float* Om = (float*)Vt2;     // [qg][mt][nt][lane][4] f32 = 32 KB
  float* Lm = (float*)Ks2;     // [qg][mt][lane] f32 = 2 KB
  if (kg == 1){
    #pragma unroll
    for (int mt=0;mt<2;++mt){
      #pragma unroll
      for (int nt=0;nt<4;++nt)
        *(floatx4*)&Om[(((qg*2+mt)*4+nt)*64 + lane)*4] = O[mt][nt];
      Lm[(qg*2+mt)*64 + lane] = l_i[mt];
    }
  }
  __syncthreads();
  if (kg == 0){
    #pragma unroll
    for (int mt=0;mt<2;++mt){
      l_i[mt] += Lm[(qg*2+mt)*64 + lane];
      #pragma unroll
      for (int nt=0;nt<4;++nt)
        O[mt][nt] += *(const floatx4*)&Om[(((qg*2+mt)*4+nt)*64 + lane)*4];
    }
    // reduce l over quads (keys spread across quads+regs); lane&15 = q
    #pragma unroll
    for (int mt=0;mt<2;++mt){
      float l = l_i[mt];
      l += __shfl_xor(l, 16, 64);
      l += __shfl_xor(l, 32, 64);
      float invl = 1.f / l;
      int qrow = qt*128 + qg*32 + mt*16 + c;
      size_t rb = ((size_t)b*N_ + qrow)*(size_t)D_;
      #pragma unroll
      for (int nt=0;nt<4;++nt){
        int d0 = h*DH_ + nt*16 + quad*4;     // 4 consecutive d per lane
        uint2v pv;
        pv.x = pk2(O[mt][nt][0]*invl, O[mt][nt][1]*invl);
        pv.y = pk2(O[mt][nt][2]*invl, O[mt][nt][3]*invl);
        *(uint2v*)(o + rb + swz(d0, qrow)) = pv;   // swz keeps 4-short runs intact
      }
    }
  }
}

extern "C" void kernel_launch(void* const* d_in, const int* in_sizes, int n_in,
                              void* d_out, int out_size, void* d_ws, size_t ws_size,
                              hipStream_t stream){
  const float* x      = (const float*)d_in[0];
  const float* coords = (const float*)d_in[1];
  const float* ln1_w  = (const float*)d_in[2];
  const float* ln1_b  = (const float*)d_in[3];
  const float* ln2_w  = (const float*)d_in[4];
  const float* ln2_b  = (const float*)d_in[5];
  const float* Wqkv   = (const float*)d_in[6];
  const float* bqkv   = (const float*)d_in[7];
  const float* Wo     = (const float*)d_in[8];
  const float* bo     = (const float*)d_in[9];
  const float* Wc     = (const float*)d_in[10];
  // d_in[11] = bc: constant over softmax axis -> no effect on output
  const float* W1     = (const float*)d_in[12];
  const float* b1     = (const float*)d_in[13];
  const float* W2     = (const float*)d_in[14];
  const float* b2     = (const float*)d_in[15];
  const float* W3     = (const float*)d_in[16];
  const float* b3     = (const float*)d_in[17];

  // ws layout (peak 40.2 MB), all bf16 raw shorts; swizzled layouts as documented
  char* ws = (char*)d_ws;
  short* Wtqkv = (short*)(ws);                         // [1536][512]
  short* Wto   = (short*)(ws + 1572864);               // [512][512]
  short* Wt1   = (short*)(ws + 2097152);               // [1408][512]
  short* Wt2   = (short*)(ws + 3538944);               // [1408][512]
  short* Wt3   = (short*)(ws + 4980736);               // [512][1408]
  float* tv    = (float*)(ws + 6422528);               // [32][2048]
  short* h     = (short*)(ws + 6684672);               // [8192][512]
  short* qb    = (short*)(ws + 15073280);              // 8 MB
  short* kb    = (short*)(ws + 23461888);              // 8 MB
  short* vbt   = (short*)(ws + 31850496);              // 8 MB  [bh][hd][n]
  short* o     = h;                                    // alias: h dead after qkv
  short* h2    = h;                                    // alias: o dead after wo
  short* ff    = qb;                                   // alias: q/k/v dead after attn
  float* x1    = (float*)d_out;                        // f32 [8192][512] = d_out

  // blocks: [0,3136) weights, [3136,3392) coord proj, [3392,11584) LN1
  convT_all<<<dim3(11584), dim3(256), 0, stream>>>(Wqkv, Wo, W1, W2, W3,
      Wtqkv, Wto, Wt1, Wt2, Wt3, coords, Wc, tv, x, ln1_w, ln1_b, h);
  qkv_gemm<<<dim3(12,64), dim3(256), 0, stream>>>(h, Wtqkv, bqkv, qb, kb, vbt);
  attn_mfma<<<dim3(16,8,4), dim3(512), 0, stream>>>(qb, kb, vbt, tv, o);
  gemm128<<<dim3(4,64), dim3(256), 0, stream>>>(o, 512, Wto, 512, bo, x, x1);
  ln_kernel<<<dim3(ROWS_), dim3(256), 0, stream>>>(x1, ln2_w, ln2_b, h2);
  gate_gemm<<<dim3(11,64), dim3(256), 0, stream>>>(h2, Wt1, Wt2, b1, b2, ff);
  gemm128<<<dim3(4,64), dim3(256), 0, stream>>>(ff, HIDP, Wt3, HIDP, b3, x1, x1);
}

// Round 3
// 321.391 us; speedup vs baseline: 1.1205x; 1.1205x over previous
//
#include <hip/hip_runtime.h>
#include <hip/hip_bf16.h>
#include <math.h>

#define B_   4
#define N_   2048
#define D_   512
#define H_   8
#define DH_  64
#define C_   3
#define HID_ 1365
#define HIDP 1408          // padded HID (11 * 128)
#define ROWS_ (B_*N_)      // 8192
#define TD_  (3*D_)        // 1536

typedef __attribute__((ext_vector_type(8))) short short8;   // 8 bf16 = 4 VGPR
typedef __attribute__((ext_vector_type(4))) float floatx4;
typedef __attribute__((ext_vector_type(2))) unsigned uint2v;

#define MFMA16(a,b,c) __builtin_amdgcn_mfma_f32_16x16x32_bf16(a,b,c,0,0,0)

typedef __attribute__((address_space(3))) unsigned lds_u32;
typedef __attribute__((address_space(1))) unsigned glb_u32;

__device__ __forceinline__ short sh(float v){
  union { __hip_bfloat16 b; short s; } u;
  u.b = __float2bfloat16(v);
  return u.s;
}

// pack two floats into one u32 of 2 bf16 (low = a); compiler fuses to cvt_pk
__device__ __forceinline__ unsigned pk2(float a, float b){
  union { short s[2]; unsigned u; } z;
  z.s[0] = sh(a); z.s[1] = sh(b);
  return z.u;
}

// global-layout segment swizzle: within each 64-short k-block, 16B segment s -> s ^ (row&7)
__device__ __forceinline__ int swz(int col, int row){
  return (col & ~63) | (col & 7) | ((((col >> 3) & 7) ^ (row & 7)) << 3);
}

// async global->LDS stage: ROWS rows of PITCH shorts (16B-swizzled global layout assumed).
template<int ROWS, int PITCH, int WAVES = 4>
__device__ __forceinline__ void stageG(short* __restrict__ lds,
    const short* __restrict__ g, int ldg, int t){
  const int LPR = PITCH/8;          // lanes per row
  const int RPI = 64/LPR;           // rows per instruction
  const int PW  = (ROWS/RPI)/WAVES; // instructions per wave
  int lane = t & 63, w = t >> 6;
  #pragma unroll
  for (int i = 0; i < PW; ++i){
    int r0  = (w*PW + i)*RPI;
    int row = r0 + lane/LPR;
    const short* ga = g + (size_t)row*ldg + (lane % LPR)*8;
    short* la = lds + r0*PITCH;     // wave-uniform; HW adds lane*16B
    __builtin_amdgcn_global_load_lds((const glb_u32*)ga, (lds_u32*)la, 16, 0, 0);
  }
}

// MFMA fragment from unpadded swizzled LDS tile
__device__ __forceinline__ short8 fragS(const short* __restrict__ lds, int pitch,
    int mbase, int lane, int kk){
  int row  = mbase + (lane & 15);
  int seg  = (kk >> 3) + (lane >> 4);
  int phys = seg ^ (row & 7);
  return *(const short8*)(lds + row*pitch + phys*8);
}

// ---------------- merged: weight transpose-convert (swizzled) + coord proj + LN1 ----------------
__global__ __launch_bounds__(256) void convT_all(
    const float* __restrict__ Wqkv, const float* __restrict__ Wo,
    const float* __restrict__ W1, const float* __restrict__ W2,
    const float* __restrict__ W3,
    short* __restrict__ Wtqkv, short* __restrict__ Wto,
    short* __restrict__ Wt1, short* __restrict__ Wt2, short* __restrict__ Wt3,
    const float* __restrict__ coords, const float* __restrict__ Wc,
    float* __restrict__ tv,
    const float* __restrict__ x, const float* __restrict__ ln1_w,
    const float* __restrict__ ln1_b, short* __restrict__ h){
  int id = blockIdx.x;
  int t = threadIdx.x;
  if (id >= 3392){            // ---- LN1 rows ----
    int row = id - 3392;
    size_t base = (size_t)row * D_;
    float v0 = x[base + t];
    float v1 = x[base + t + 256];
    float s  = v0 + v1;
    float s2 = v0*v0 + v1*v1;
    #pragma unroll
    for (int off = 32; off >= 1; off >>= 1){
      s  += __shfl_xor(s,  off, 64);
      s2 += __shfl_xor(s2, off, 64);
    }
    __shared__ float red[8];
    int lane = t & 63, wv = t >> 6;
    if (lane == 0){ red[wv] = s; red[4+wv] = s2; }
    __syncthreads();
    float sum  = red[0]+red[1]+red[2]+red[3];
    float sum2 = red[4]+red[5]+red[6]+red[7];
    float mean = sum * (1.0f/D_);
    float var  = sum2 * (1.0f/D_) - mean*mean;
    float inv  = rsqrtf(fmaxf(var, 0.f) + 1e-5f);
    h[base + swz(t,     row)] = sh((v0-mean)*inv*ln1_w[t]     + ln1_b[t]);
    h[base + swz(t+256, row)] = sh((v1-mean)*inv*ln1_w[t+256] + ln1_b[t+256]);
    return;
  }
  if (id >= 3136){            // ---- coord projection: tv = coords·Wc * log2(e) ----
    int idx = (id - 3136)*256 + t;
    int n = idx & (N_-1);
    int hh = (idx >> 11) & (H_-1);
    int b = idx >> 14;
    float s = 0.f;
    #pragma unroll
    for (int cc = 0; cc < C_; ++cc)
      s += coords[((size_t)(b*N_+n))*C_ + cc] * Wc[cc*H_ + hh];
    tv[idx] = s * 1.44269504f;       // pre-scaled into exp2 domain
    return;
  }
  // ---- weight transpose-convert ----
  __shared__ float tile[32][33];
  const float* in; short* out; int K, NN, Kp, nx;
  if (id < 768)      { in=Wqkv; out=Wtqkv; K=512;  NN=1536; Kp=512;  nx=48; }
  else if (id < 1024){ in=Wo;   out=Wto;   K=512;  NN=512;  Kp=512;  nx=16; id-=768; }
  else if (id < 1728){ in=W1;   out=Wt1;   K=512;  NN=HID_; Kp=512;  nx=44; id-=1024; }
  else if (id < 2432){ in=W2;   out=Wt2;   K=512;  NN=HID_; Kp=512;  nx=44; id-=1728; }
  else               { in=W3;   out=Wt3;   K=HID_; NN=512;  Kp=HIDP; nx=16; id-=2432; }
  int nt0 = (id % nx)*32, kt0 = (id / nx)*32;
  int r = t >> 5, cc = t & 31;
  #pragma unroll
  for (int i=0;i<4;++i){
    int k = kt0 + i*8 + r, n = nt0 + cc;
    tile[i*8+r][cc] = (k<K && n<NN) ? in[(size_t)k*NN + n] : 0.f;
  }
  __syncthreads();
  #pragma unroll
  for (int i=0;i<4;++i){
    int n = nt0 + i*8 + r, k = kt0 + cc;
    out[(size_t)n*Kp + swz(k, n)] = sh(tile[cc][i*8+r]);
  }
}

// ---------------- LayerNorm (f32 in, swizzled bf16 out) ----------------
__global__ __launch_bounds__(256) void ln_kernel(const float* __restrict__ x,
        const float* __restrict__ w, const float* __restrict__ b,
        short* __restrict__ out){
  int row = blockIdx.x;
  size_t base = (size_t)row * D_;
  int t = threadIdx.x;
  float v0 = x[base + t];
  float v1 = x[base + t + 256];
  float s  = v0 + v1;
  float s2 = v0*v0 + v1*v1;
  #pragma unroll
  for (int off = 32; off >= 1; off >>= 1){
    s  += __shfl_xor(s,  off, 64);
    s2 += __shfl_xor(s2, off, 64);
  }
  __shared__ float red[8];
  int lane = t & 63, wv = t >> 6;
  if (lane == 0){ red[wv] = s; red[4+wv] = s2; }
  __syncthreads();
  float sum  = red[0]+red[1]+red[2]+red[3];
  float sum2 = red[4]+red[5]+red[6]+red[7];
  float mean = sum * (1.0f/D_);
  float var  = sum2 * (1.0f/D_) - mean*mean;
  float inv  = rsqrtf(fmaxf(var, 0.f) + 1e-5f);
  out[base + swz(t,     row)] = sh((v0-mean)*inv*w[t]     + b[t]);
  out[base + swz(t+256, row)] = sh((v1-mean)*inv*w[t+256] + b[t+256]);
}

// ---------------- QKV GEMM 128x128 -> qb/kb [bh][n][hd] swz, vbt [bh][hd][n] swz ----------------
__global__ __launch_bounds__(256) void qkv_gemm(
    const short* __restrict__ A, const short* __restrict__ Bt,
    const float* __restrict__ bias,
    short* __restrict__ qb, short* __restrict__ kb, short* __restrict__ vbt){
  __shared__ short As[128*64];
  __shared__ short Bs[128*64];
  int t = threadIdx.x;
  int lane = t & 63, w = t >> 6;
  int wr = (w >> 1) * 64, wc = (w & 1) * 64;
  int col0 = blockIdx.x * 128, row0 = blockIdx.y * 128;
  floatx4 acc[4][4];
  #pragma unroll
  for (int mt=0;mt<4;++mt)
    #pragma unroll
    for (int nt=0;nt<4;++nt) acc[mt][nt] = (floatx4){0.f,0.f,0.f,0.f};
  for (int k0 = 0; k0 < D_; k0 += 64){
    __syncthreads();
    stageG<128,64>(As, A  + (size_t)row0*D_ + k0, D_, t);
    stageG<128,64>(Bs, Bt + (size_t)col0*D_ + k0, D_, t);
    __syncthreads();
    #pragma unroll
    for (int kk = 0; kk < 64; kk += 32){
      short8 af[4], bf[4];
      #pragma unroll
      for (int mt=0;mt<4;++mt) af[mt] = fragS(As, 64, wr+mt*16, lane, kk);
      #pragma unroll
      for (int nt=0;nt<4;++nt) bf[nt] = fragS(Bs, 64, wc+nt*16, lane, kk);
      #pragma unroll
      for (int mt=0;mt<4;++mt)
        #pragma unroll
        for (int nt=0;nt<4;++nt)
          acc[mt][nt] = MFMA16(af[mt], bf[nt], acc[mt][nt]);
    }
  }
  int quad = lane >> 4, c = lane & 15;
  #pragma unroll
  for (int mt=0;mt<4;++mt){
    #pragma unroll
    for (int nt=0;nt<4;++nt){
      #pragma unroll
      for (int r=0;r<4;++r){
        int row = row0 + wr + mt*16 + quad*4 + r;
        int col = col0 + wc + nt*16 + c;
        float v = acc[mt][nt][r] + bias[col];
        int bidx = row >> 11, n = row & (N_-1);
        int which = col >> 9, d = col & (D_-1), hh = d >> 6, hd = d & 63;
        short sv = sh(v);
        if (which == 0)
          qb[(((size_t)(bidx*H_ + hh))*N_ + n)*DH_ + swz(hd, n)] = sv;
        else if (which == 1)
          kb[(((size_t)(bidx*H_ + hh))*N_ + n)*DH_ + swz(hd, n)] = sv;
        else  // V transposed: [bh][hd][n], n swizzled by hd
          vbt[(((size_t)(bidx*H_ + hh))*DH_ + hd)*N_ + swz(n, hd)] = sv;
      }
    }
  }
}

// ---------------- MFMA GEMM 128x64 tile, BK=64, out = acc + bias + resid (f32) ----------------
__global__ __launch_bounds__(256) void gemm64(
    const short* __restrict__ A, int lda,
    const short* __restrict__ Bt, int Ktot,
    const float* __restrict__ bias,
    const float* __restrict__ resid, float* __restrict__ outF){
  __shared__ short As[128*64];
  __shared__ short Bs[64*64];
  int t = threadIdx.x, lane = t & 63, w = t >> 6;
  int wr = w * 32;
  int col0 = blockIdx.x * 64, row0 = blockIdx.y * 128;
  floatx4 acc[2][4];
  #pragma unroll
  for (int mt=0;mt<2;++mt)
    #pragma unroll
    for (int nt=0;nt<4;++nt) acc[mt][nt] = (floatx4){0.f,0.f,0.f,0.f};
  for (int k0 = 0; k0 < Ktot; k0 += 64){
    __syncthreads();
    stageG<128,64>(As, A  + (size_t)row0*lda + k0, lda, t);
    stageG<64,64> (Bs, Bt + (size_t)col0*Ktot + k0, Ktot, t);
    __syncthreads();
    #pragma unroll
    for (int kk = 0; kk < 64; kk += 32){
      short8 af[2], bf[4];
      #pragma unroll
      for (int mt=0;mt<2;++mt) af[mt] = fragS(As, 64, wr+mt*16, lane, kk);
      #pragma unroll
      for (int nt=0;nt<4;++nt) bf[nt] = fragS(Bs, 64, nt*16, lane, kk);
      #pragma unroll
      for (int mt=0;mt<2;++mt)
        #pragma unroll
        for (int nt=0;nt<4;++nt)
          acc[mt][nt] = MFMA16(af[mt], bf[nt], acc[mt][nt]);
    }
  }
  int quad = lane >> 4, c = lane & 15;
  #pragma unroll
  for (int mt=0;mt<2;++mt){
    #pragma unroll
    for (int nt=0;nt<4;++nt){
      #pragma unroll
      for (int r=0;r<4;++r){
        int row = row0 + wr + mt*16 + quad*4 + r;
        int col = col0 + nt*16 + c;
        size_t idx = (size_t)row*D_ + col;
        outF[idx] = acc[mt][nt][r] + bias[col] + resid[idx];
      }
    }
  }
}

// ---------------- fused SwiGLU gate GEMM: 128x64 tile, dual-B, swizzled out ----------------
__global__ __launch_bounds__(256) void gate_gemm(
    const short* __restrict__ A,
    const short* __restrict__ Bt1, const short* __restrict__ Bt2,
    const float* __restrict__ b1, const float* __restrict__ b2,
    short* __restrict__ ff){
  __shared__ short As[128*64];
  __shared__ short B1s[64*64];
  __shared__ short B2s[64*64];
  int t = threadIdx.x, lane = t & 63, w = t >> 6;
  int wr = (w >> 1) * 64, wc = (w & 1) * 32;
  int col0 = blockIdx.x * 64, row0 = blockIdx.y * 128;
  floatx4 a1[4][2], a2[4][2];
  #pragma unroll
  for (int mt=0;mt<4;++mt)
    #pragma unroll
    for (int nt=0;nt<2;++nt){
      a1[mt][nt] = (floatx4){0.f,0.f,0.f,0.f};
      a2[mt][nt] = (floatx4){0.f,0.f,0.f,0.f};
    }
  for (int k0 = 0; k0 < D_; k0 += 64){
    __syncthreads();
    stageG<128,64>(As, A + (size_t)row0*D_ + k0, D_, t);
    stageG<64,64>(B1s, Bt1 + (size_t)col0*D_ + k0, D_, t);
    stageG<64,64>(B2s, Bt2 + (size_t)col0*D_ + k0, D_, t);
    __syncthreads();
    #pragma unroll
    for (int kk = 0; kk < 64; kk += 32){
      short8 af[4], f1[2], f2[2];
      #pragma unroll
      for (int mt=0;mt<4;++mt) af[mt] = fragS(As, 64, wr+mt*16, lane, kk);
      #pragma unroll
      for (int nt=0;nt<2;++nt){
        f1[nt] = fragS(B1s, 64, wc+nt*16, lane, kk);
        f2[nt] = fragS(B2s, 64, wc+nt*16, lane, kk);
      }
      #pragma unroll
      for (int mt=0;mt<4;++mt)
        #pragma unroll
        for (int nt=0;nt<2;++nt){
          a1[mt][nt] = MFMA16(af[mt], f1[nt], a1[mt][nt]);
          a2[mt][nt] = MFMA16(af[mt], f2[nt], a2[mt][nt]);
        }
    }
  }
  int quad = lane >> 4, c = lane & 15;
  #pragma unroll
  for (int mt=0;mt<4;++mt){
    #pragma unroll
    for (int nt=0;nt<2;++nt){
      #pragma unroll
      for (int r=0;r<4;++r){
        int row = row0 + wr + mt*16 + quad*4 + r;
        int col = col0 + wc + nt*16 + c;
        float g1 = a1[mt][nt][r] + (col < HID_ ? b1[col] : 0.f);
        float g2 = a2[mt][nt][r] + (col < HID_ ? b2[col] : 0.f);
        float sig = 1.f / (1.f + __expf(-g1));
        ff[(size_t)row*HIDP + swz(col, row)] = sh(g1*sig*g2);
      }
    }
  }
}

// ---------------- MFMA flash attention, swapped-QK^T, in-register softmax ----------------
// 512 threads = 8 waves: 4 q-groups (32 rows each) x 2 key-halves (64 keys each).
// 4 waves/SIMD for latency hiding; key-half partials (O,l) merged via LDS at end
// (fixed-max softmax -> partials merge by plain addition).
#define EXP2SC 0.18033688011112042f   // 0.125 * log2(e)
__global__ __launch_bounds__(512,4) void attn_mfma(
    const short* __restrict__ qb, const short* __restrict__ kbuf,
    const short* __restrict__ vbt, const float* __restrict__ tv,
    short* __restrict__ o){
  __shared__ short Ks2[2][128*64];        // [key][hd] swizzled
  __shared__ short Vt2[2][64*128];        // [hd][key] swizzled
  __shared__ __align__(16) float tsAll[2048];  // tv row (pre-scaled by log2e)
  int qt = blockIdx.x, h = blockIdx.y, b = blockIdx.z;
  int bh = b*H_ + h;
  int t = threadIdx.x, lane = t & 63, w = t >> 6;
  int qg = w & 3, kg = w >> 2;            // q-group, key-half
  int quad = lane >> 4, c = lane & 15;
  const short* Kbase = kbuf + (size_t)bh*N_*DH_;
  const short* Vbase = vbt  + (size_t)bh*DH_*N_;

  *(floatx4*)&tsAll[t*4] = *(const floatx4*)&tv[(size_t)bh*N_ + t*4];
  // stage Q into buffer 1; stage kt=0 K/V into buffer 0
  stageG<128,64,8>(Ks2[1], qb + ((size_t)bh*N_ + qt*128)*DH_, DH_, t);
  stageG<128,64,8>(Ks2[0], Kbase, DH_, t);
  stageG<64,128,8>(Vt2[0], Vbase, N_, t);
  __syncthreads();
  short8 qf[2][2];
  #pragma unroll
  for (int mt=0;mt<2;++mt)
    #pragma unroll
    for (int kh=0;kh<2;++kh)
      qf[mt][kh] = fragS(Ks2[1], 64, qg*32 + mt*16, lane, kh*32);
  floatx4 O[2][4];
  float l_i[2] = {0.f, 0.f};
  #pragma unroll
  for (int mt=0;mt<2;++mt)
    #pragma unroll
    for (int nt=0;nt<4;++nt) O[mt][nt] = (floatx4){0.f,0.f,0.f,0.f};
  __syncthreads();   // all waves finished reading Q before buffer 1 is restaged

  for (int kt = 0; kt < N_/128; ++kt){
    int cur = kt & 1;
    if (kt + 1 < N_/128){   // issue next-tile stage; overlaps this tile's compute
      stageG<128,64,8>(Ks2[cur^1], Kbase + (size_t)(kt+1)*128*DH_, DH_, t);
      stageG<64,128,8>(Vt2[cur^1], Vbase + (kt+1)*128, N_, t);
    }
    const short* Kc  = Ks2[cur];
    const short* Vc  = Vt2[cur];
    const float* tsc = tsAll + kt*128;
    #pragma unroll
    for (int kb = 0; kb < 2; ++kb){        // this wave's two 32-key blocks
      int kb4 = kg*2 + kb;
      floatx4 St[2][2];
      #pragma unroll
      for (int i=0;i<2;++i){
        St[i][0] = (floatx4){0.f,0.f,0.f,0.f};
        St[i][1] = (floatx4){0.f,0.f,0.f,0.f};
      }
      #pragma unroll
      for (int kh=0;kh<2;++kh){
        short8 kf0 = fragS(Kc, 64, kb4*32,      lane, kh*32);
        short8 kf1 = fragS(Kc, 64, kb4*32 + 16, lane, kh*32);
        #pragma unroll
        for (int mt=0;mt<2;++mt){
          St[0][mt] = MFMA16(kf0, qf[mt][kh], St[0][mt]);   // C[key][q]
          St[1][mt] = MFMA16(kf1, qf[mt][kh], St[1][mt]);
        }
      }
      floatx4 t0 = *(const floatx4*)&tsc[kb4*32 + quad*4];
      floatx4 t1 = *(const floatx4*)&tsc[kb4*32 + 16 + quad*4];
      short8 pbf[2];
      #pragma unroll
      for (int mt=0;mt<2;++mt){
        float p0[4], p1[4];
        #pragma unroll
        for (int r=0;r<4;++r){
          p0[r] = __builtin_amdgcn_exp2f(fmaf(St[0][mt][r], EXP2SC, -t0[r]));
          p1[r] = __builtin_amdgcn_exp2f(fmaf(St[1][mt][r], EXP2SC, -t1[r]));
        }
        l_i[mt] += (p0[0]+p0[1]) + (p0[2]+p0[3]) + (p1[0]+p1[1]) + (p1[2]+p1[3]);
        // pack consecutive-key pairs, then quad-regroup to the B-fragment layout
        unsigned X0 = pk2(p0[0], p0[1]), X1 = pk2(p0[2], p0[3]);
        unsigned Y0 = pk2(p1[0], p1[1]), Y1 = pk2(p1[2], p1[3]);
        auto u0 = __builtin_amdgcn_permlane32_swap(X0, Y0, false, false);
        auto v0 = __builtin_amdgcn_permlane16_swap(u0[0], u0[1], false, false);
        auto u1 = __builtin_amdgcn_permlane32_swap(X1, Y1, false, false);
        auto v1 = __builtin_amdgcn_permlane16_swap(u1[0], u1[1], false, false);
        union { short8 s; unsigned uu[4]; } pb;
        pb.uu[0] = v0[0]; pb.uu[1] = v1[0]; pb.uu[2] = v0[1]; pb.uu[3] = v1[1];
        pbf[mt] = pb.s;
      }
      // O^T += V^T · P^T   (C[d][q])
      #pragma unroll
      for (int nt=0;nt<4;++nt){
        short8 vf = fragS(Vc, 128, nt*16, lane, kb4*32);
        #pragma unroll
        for (int mt=0;mt<2;++mt)
          O[mt][nt] = MFMA16(vf, pbf[mt], O[mt][nt]);
      }
    }
    __syncthreads();
  }
  // ---- merge key-half partials via LDS overlays on dead K/V buffers ----
  float* Om = (float*)Vt2;     // [qg][mt][nt][lane][4] f32 = 32 KB
  float* Lm = (float*)Ks2;     // [qg][mt][lane] f32 = 2 KB
  if (kg == 1){
    #pragma unroll
    for (int mt=0;mt<2;++mt){
      #pragma unroll
      for (int nt=0;nt<4;++nt)
        *(floatx4*)&Om[(((qg*2+mt)*4+nt)*64 + lane)*4] = O[mt][nt];
      Lm[(qg*2+mt)*64 + lane] = l_i[mt];
    }
  }
  __syncthreads();
  if (kg == 0){
    #pragma unroll
    for (int mt=0;mt<2;++mt){
      l_i[mt] += Lm[(qg*2+mt)*64 + lane];
      #pragma unroll
      for (int nt=0;nt<4;++nt)
        O[mt][nt] += *(const floatx4*)&Om[(((qg*2+mt)*4+nt)*64 + lane)*4];
    }
    // reduce l over quads (keys spread across quads+regs); lane&15 = q
    #pragma unroll
    for (int mt=0;mt<2;++mt){
      float l = l_i[mt];
      l += __shfl_xor(l, 16, 64);
      l += __shfl_xor(l, 32, 64);
      float invl = 1.f / l;
      int qrow = qt*128 + qg*32 + mt*16 + c;
      size_t rb = ((size_t)b*N_ + qrow)*(size_t)D_;
      #pragma unroll
      for (int nt=0;nt<4;++nt){
        int d0 = h*DH_ + nt*16 + quad*4;     // 4 consecutive d per lane
        uint2v pv;
        pv.x = pk2(O[mt][nt][0]*invl, O[mt][nt][1]*invl);
        pv.y = pk2(O[mt][nt][2]*invl, O[mt][nt][3]*invl);
        *(uint2v*)(o + rb + swz(d0, qrow)) = pv;   // swz keeps 4-short runs intact
      }
    }
  }
}

extern "C" void kernel_launch(void* const* d_in, const int* in_sizes, int n_in,
                              void* d_out, int out_size, void* d_ws, size_t ws_size,
                              hipStream_t stream){
  const float* x      = (const float*)d_in[0];
  const float* coords = (const float*)d_in[1];
  const float* ln1_w  = (const float*)d_in[2];
  const float* ln1_b  = (const float*)d_in[3];
  const float* ln2_w  = (const float*)d_in[4];
  const float* ln2_b  = (const float*)d_in[5];
  const float* Wqkv   = (const float*)d_in[6];
  const float* bqkv   = (const float*)d_in[7];
  const float* Wo     = (const float*)d_in[8];
  const float* bo     = (const float*)d_in[9];
  const float* Wc     = (const float*)d_in[10];
  // d_in[11] = bc: constant over softmax axis -> no effect on output
  const float* W1     = (const float*)d_in[12];
  const float* b1     = (const float*)d_in[13];
  const float* W2     = (const float*)d_in[14];
  const float* b2     = (const float*)d_in[15];
  const float* W3     = (const float*)d_in[16];
  const float* b3     = (const float*)d_in[17];

  // ws layout (peak 40.2 MB), all bf16 raw shorts; swizzled layouts as documented
  char* ws = (char*)d_ws;
  short* Wtqkv = (short*)(ws);                         // [1536][512]
  short* Wto   = (short*)(ws + 1572864);               // [512][512]
  short* Wt1   = (short*)(ws + 2097152);               // [1408][512]
  short* Wt2   = (short*)(ws + 3538944);               // [1408][512]
  short* Wt3   = (short*)(ws + 4980736);               // [512][1408]
  float* tv    = (float*)(ws + 6422528);               // [32][2048]
  short* h     = (short*)(ws + 6684672);               // [8192][512]
  short* qb    = (short*)(ws + 15073280);              // 8 MB
  short* kb    = (short*)(ws + 23461888);              // 8 MB
  short* vbt   = (short*)(ws + 31850496);              // 8 MB  [bh][hd][n]
  short* o     = h;                                    // alias: h dead after qkv
  short* h2    = h;                                    // alias: o dead after wo
  short* ff    = qb;                                   // alias: q/k/v dead after attn
  float* x1    = (float*)d_out;                        // f32 [8192][512] = d_out

  // blocks: [0,3136) weights, [3136,3392) coord proj, [3392,11584) LN1
  convT_all<<<dim3(11584), dim3(256), 0, stream>>>(Wqkv, Wo, W1, W2, W3,
      Wtqkv, Wto, Wt1, Wt2, Wt3, coords, Wc, tv, x, ln1_w, ln1_b, h);
  qkv_gemm<<<dim3(12,64), dim3(256), 0, stream>>>(h, Wtqkv, bqkv, qb, kb, vbt);
  attn_mfma<<<dim3(16,8,4), dim3(512), 0, stream>>>(qb, kb, vbt, tv, o);
  gemm64<<<dim3(8,64), dim3(256), 0, stream>>>(o, 512, Wto, 512, bo, x, x1);
  ln_kernel<<<dim3(ROWS_), dim3(256), 0, stream>>>(x1, ln2_w, ln2_b, h2);
  gate_gemm<<<dim3(22,64), dim3(256), 0, stream>>>(h2, Wt1, Wt2, b1, b2, ff);
  gemm64<<<dim3(8,64), dim3(256), 0, stream>>>(ff, HIDP, Wt3, HIDP, b3, x1, x1);
}

// Round 4
// 313.566 us; speedup vs baseline: 1.1484x; 1.0250x over previous
//
#include <hip/hip_runtime.h>
#include <hip/hip_bf16.h>
#include <math.h>

#define B_   4
#define N_   2048
#define D_   512
#define H_   8
#define DH_  64
#define C_   3
#define HID_ 1365
#define HIDP 1408          // padded HID (11 * 128)
#define ROWS_ (B_*N_)      // 8192
#define TD_  (3*D_)        // 1536

typedef __attribute__((ext_vector_type(8))) short short8;   // 8 bf16 = 4 VGPR
typedef __attribute__((ext_vector_type(4))) float floatx4;
typedef __attribute__((ext_vector_type(2))) unsigned uint2v;

#define MFMA16(a,b,c) __builtin_amdgcn_mfma_f32_16x16x32_bf16(a,b,c,0,0,0)

typedef __attribute__((address_space(3))) unsigned lds_u32;
typedef __attribute__((address_space(1))) unsigned glb_u32;

__device__ __forceinline__ short sh(float v){
  union { __hip_bfloat16 b; short s; } u;
  u.b = __float2bfloat16(v);
  return u.s;
}

// pack two floats into one u32 of 2 bf16 (low = a); compiler fuses to cvt_pk
__device__ __forceinline__ unsigned pk2(float a, float b){
  union { short s[2]; unsigned u; } z;
  z.s[0] = sh(a); z.s[1] = sh(b);
  return z.u;
}

// global-layout segment swizzle: within each 64-short k-block, 16B segment s -> s ^ (row&7)
__device__ __forceinline__ int swz(int col, int row){
  return (col & ~63) | (col & 7) | ((((col >> 3) & 7) ^ (row & 7)) << 3);
}

// async global->LDS stage: ROWS rows of PITCH shorts (16B-swizzled global layout assumed).
template<int ROWS, int PITCH, int WAVES = 4>
__device__ __forceinline__ void stageG(short* __restrict__ lds,
    const short* __restrict__ g, int ldg, int t){
  const int LPR = PITCH/8;          // lanes per row
  const int RPI = 64/LPR;           // rows per instruction
  const int PW  = (ROWS/RPI)/WAVES; // instructions per wave
  int lane = t & 63, w = t >> 6;
  #pragma unroll
  for (int i = 0; i < PW; ++i){
    int r0  = (w*PW + i)*RPI;
    int row = r0 + lane/LPR;
    const short* ga = g + (size_t)row*ldg + (lane % LPR)*8;
    short* la = lds + r0*PITCH;     // wave-uniform; HW adds lane*16B
    __builtin_amdgcn_global_load_lds((const glb_u32*)ga, (lds_u32*)la, 16, 0, 0);
  }
}

// MFMA fragment from unpadded swizzled LDS tile
__device__ __forceinline__ short8 fragS(const short* __restrict__ lds, int pitch,
    int mbase, int lane, int kk){
  int row  = mbase + (lane & 15);
  int seg  = (kk >> 3) + (lane >> 4);
  int phys = seg ^ (row & 7);
  return *(const short8*)(lds + row*pitch + phys*8);
}

// ---------------- merged: weight transpose-convert (swizzled) + coord proj + LN1 ----------------
__global__ __launch_bounds__(256) void convT_all(
    const float* __restrict__ Wqkv, const float* __restrict__ Wo,
    const float* __restrict__ W1, const float* __restrict__ W2,
    const float* __restrict__ W3,
    short* __restrict__ Wtqkv, short* __restrict__ Wto,
    short* __restrict__ Wt1, short* __restrict__ Wt2, short* __restrict__ Wt3,
    const float* __restrict__ coords, const float* __restrict__ Wc,
    float* __restrict__ tv,
    const float* __restrict__ x, const float* __restrict__ ln1_w,
    const float* __restrict__ ln1_b, short* __restrict__ h){
  int id = blockIdx.x;
  int t = threadIdx.x;
  if (id >= 3392){            // ---- LN1 rows (float2 loads, packed u32 store) ----
    int row = id - 3392;
    size_t base = (size_t)row * D_;
    float2 u = *(const float2*)&x[base + 2*t];
    float s  = u.x + u.y;
    float s2 = u.x*u.x + u.y*u.y;
    #pragma unroll
    for (int off = 32; off >= 1; off >>= 1){
      s  += __shfl_xor(s,  off, 64);
      s2 += __shfl_xor(s2, off, 64);
    }
    __shared__ float red[8];
    int lane = t & 63, wv = t >> 6;
    if (lane == 0){ red[wv] = s; red[4+wv] = s2; }
    __syncthreads();
    float sum  = red[0]+red[1]+red[2]+red[3];
    float sum2 = red[4]+red[5]+red[6]+red[7];
    float mean = sum * (1.0f/D_);
    float var  = sum2 * (1.0f/D_) - mean*mean;
    float inv  = rsqrtf(fmaxf(var, 0.f) + 1e-5f);
    float2 wv2 = *(const float2*)&ln1_w[2*t];
    float2 bv2 = *(const float2*)&ln1_b[2*t];
    *(unsigned*)(h + base + swz(2*t, row)) =
        pk2((u.x-mean)*inv*wv2.x + bv2.x, (u.y-mean)*inv*wv2.y + bv2.y);
    return;
  }
  if (id >= 3136){            // ---- coord projection: tv = coords·Wc * log2(e) ----
    int idx = (id - 3136)*256 + t;
    int n = idx & (N_-1);
    int hh = (idx >> 11) & (H_-1);
    int b = idx >> 14;
    float s = 0.f;
    #pragma unroll
    for (int cc = 0; cc < C_; ++cc)
      s += coords[((size_t)(b*N_+n))*C_ + cc] * Wc[cc*H_ + hh];
    tv[idx] = s * 1.44269504f;       // pre-scaled into exp2 domain
    return;
  }
  // ---- weight transpose-convert ----
  __shared__ float tile[32][33];
  const float* in; short* out; int K, NN, Kp, nx;
  if (id < 768)      { in=Wqkv; out=Wtqkv; K=512;  NN=1536; Kp=512;  nx=48; }
  else if (id < 1024){ in=Wo;   out=Wto;   K=512;  NN=512;  Kp=512;  nx=16; id-=768; }
  else if (id < 1728){ in=W1;   out=Wt1;   K=512;  NN=HID_; Kp=512;  nx=44; id-=1024; }
  else if (id < 2432){ in=W2;   out=Wt2;   K=512;  NN=HID_; Kp=512;  nx=44; id-=1728; }
  else               { in=W3;   out=Wt3;   K=HID_; NN=512;  Kp=HIDP; nx=16; id-=2432; }
  int nt0 = (id % nx)*32, kt0 = (id / nx)*32;
  int r = t >> 5, cc = t & 31;
  #pragma unroll
  for (int i=0;i<4;++i){
    int k = kt0 + i*8 + r, n = nt0 + cc;
    tile[i*8+r][cc] = (k<K && n<NN) ? in[(size_t)k*NN + n] : 0.f;
  }
  __syncthreads();
  #pragma unroll
  for (int i=0;i<4;++i){
    int n = nt0 + i*8 + r, k = kt0 + cc;
    out[(size_t)n*Kp + swz(k, n)] = sh(tile[cc][i*8+r]);
  }
}

// ---------------- LayerNorm (f32 in, swizzled bf16 out); float2 loads, u32 store ----------------
__global__ __launch_bounds__(256) void ln_kernel(const float* __restrict__ x,
        const float* __restrict__ w, const float* __restrict__ b,
        short* __restrict__ out){
  int row = blockIdx.x;
  size_t base = (size_t)row * D_;
  int t = threadIdx.x;
  float2 u = *(const float2*)&x[base + 2*t];
  float s  = u.x + u.y;
  float s2 = u.x*u.x + u.y*u.y;
  #pragma unroll
  for (int off = 32; off >= 1; off >>= 1){
    s  += __shfl_xor(s,  off, 64);
    s2 += __shfl_xor(s2, off, 64);
  }
  __shared__ float red[8];
  int lane = t & 63, wv = t >> 6;
  if (lane == 0){ red[wv] = s; red[4+wv] = s2; }
  __syncthreads();
  float sum  = red[0]+red[1]+red[2]+red[3];
  float sum2 = red[4]+red[5]+red[6]+red[7];
  float mean = sum * (1.0f/D_);
  float var  = sum2 * (1.0f/D_) - mean*mean;
  float inv  = rsqrtf(fmaxf(var, 0.f) + 1e-5f);
  float2 wv2 = *(const float2*)&w[2*t];
  float2 bv2 = *(const float2*)&b[2*t];
  *(unsigned*)(out + base + swz(2*t, row)) =
      pk2((u.x-mean)*inv*wv2.x + bv2.x, (u.y-mean)*inv*wv2.y + bv2.y);
}

// ---------------- QKV GEMM 128x128 -> qb/kb [bh][n][hd] swz, vbt [bh][hd][n] swz ----------------
__global__ __launch_bounds__(256) void qkv_gemm(
    const short* __restrict__ A, const short* __restrict__ Bt,
    const float* __restrict__ bias,
    short* __restrict__ qb, short* __restrict__ kb, short* __restrict__ vbt){
  __shared__ short As[128*64];
  __shared__ short Bs[128*64];
  int t = threadIdx.x;
  int lane = t & 63, w = t >> 6;
  int wr = (w >> 1) * 64, wc = (w & 1) * 64;
  int col0 = blockIdx.x * 128, row0 = blockIdx.y * 128;
  floatx4 acc[4][4];
  #pragma unroll
  for (int mt=0;mt<4;++mt)
    #pragma unroll
    for (int nt=0;nt<4;++nt) acc[mt][nt] = (floatx4){0.f,0.f,0.f,0.f};
  for (int k0 = 0; k0 < D_; k0 += 64){
    __syncthreads();
    stageG<128,64>(As, A  + (size_t)row0*D_ + k0, D_, t);
    stageG<128,64>(Bs, Bt + (size_t)col0*D_ + k0, D_, t);
    __syncthreads();
    #pragma unroll
    for (int kk = 0; kk < 64; kk += 32){
      short8 af[4], bf[4];
      #pragma unroll
      for (int mt=0;mt<4;++mt) af[mt] = fragS(As, 64, wr+mt*16, lane, kk);
      #pragma unroll
      for (int nt=0;nt<4;++nt) bf[nt] = fragS(Bs, 64, wc+nt*16, lane, kk);
      #pragma unroll
      for (int mt=0;mt<4;++mt)
        #pragma unroll
        for (int nt=0;nt<4;++nt)
          acc[mt][nt] = MFMA16(af[mt], bf[nt], acc[mt][nt]);
    }
  }
  int quad = lane >> 4, c = lane & 15;
  #pragma unroll
  for (int mt=0;mt<4;++mt){
    #pragma unroll
    for (int nt=0;nt<4;++nt){
      #pragma unroll
      for (int r=0;r<4;++r){
        int row = row0 + wr + mt*16 + quad*4 + r;
        int col = col0 + wc + nt*16 + c;
        float v = acc[mt][nt][r] + bias[col];
        int bidx = row >> 11, n = row & (N_-1);
        int which = col >> 9, d = col & (D_-1), hh = d >> 6, hd = d & 63;
        short sv = sh(v);
        if (which == 0)
          qb[(((size_t)(bidx*H_ + hh))*N_ + n)*DH_ + swz(hd, n)] = sv;
        else if (which == 1)
          kb[(((size_t)(bidx*H_ + hh))*N_ + n)*DH_ + swz(hd, n)] = sv;
        else  // V transposed: [bh][hd][n], n swizzled by hd
          vbt[(((size_t)(bidx*H_ + hh))*DH_ + hd)*N_ + swz(n, hd)] = sv;
      }
    }
  }
}

// ---------------- MFMA GEMM 128x64 tile, BK=64, double-buffered 2-phase pipeline ----------------
__global__ __launch_bounds__(256) void gemm64(
    const short* __restrict__ A, int lda,
    const short* __restrict__ Bt, int Ktot,
    const float* __restrict__ bias,
    const float* __restrict__ resid, float* __restrict__ outF){
  __shared__ short As[2][128*64];
  __shared__ short Bs[2][64*64];
  int t = threadIdx.x, lane = t & 63, w = t >> 6;
  int wr = w * 32;
  int col0 = blockIdx.x * 64, row0 = blockIdx.y * 128;
  floatx4 acc[2][4];
  #pragma unroll
  for (int mt=0;mt<2;++mt)
    #pragma unroll
    for (int nt=0;nt<4;++nt) acc[mt][nt] = (floatx4){0.f,0.f,0.f,0.f};
  stageG<128,64>(As[0], A  + (size_t)row0*lda, lda, t);
  stageG<64,64> (Bs[0], Bt + (size_t)col0*Ktot, Ktot, t);
  const int NT = Ktot >> 6;
  for (int ti = 0; ti < NT; ++ti){
    int cur = ti & 1;
    __syncthreads();   // stage(cur) complete (per-wave vmcnt drain) + buf[cur^1] free
    if (ti + 1 < NT){
      stageG<128,64>(As[cur^1], A  + (size_t)row0*lda + (ti+1)*64, lda, t);
      stageG<64,64> (Bs[cur^1], Bt + (size_t)col0*Ktot + (ti+1)*64, Ktot, t);
    }
    #pragma unroll
    for (int kk = 0; kk < 64; kk += 32){
      short8 af[2], bf[4];
      #pragma unroll
      for (int mt=0;mt<2;++mt) af[mt] = fragS(As[cur], 64, wr+mt*16, lane, kk);
      #pragma unroll
      for (int nt=0;nt<4;++nt) bf[nt] = fragS(Bs[cur], 64, nt*16, lane, kk);
      #pragma unroll
      for (int mt=0;mt<2;++mt)
        #pragma unroll
        for (int nt=0;nt<4;++nt)
          acc[mt][nt] = MFMA16(af[mt], bf[nt], acc[mt][nt]);
    }
  }
  int quad = lane >> 4, c = lane & 15;
  #pragma unroll
  for (int mt=0;mt<2;++mt){
    #pragma unroll
    for (int nt=0;nt<4;++nt){
      #pragma unroll
      for (int r=0;r<4;++r){
        int row = row0 + wr + mt*16 + quad*4 + r;
        int col = col0 + nt*16 + c;
        size_t idx = (size_t)row*D_ + col;
        outF[idx] = acc[mt][nt][r] + bias[col] + resid[idx];
      }
    }
  }
}

// ---------------- fused SwiGLU gate GEMM: 128x64 tile, dual-B, swizzled out ----------------
__global__ __launch_bounds__(256) void gate_gemm(
    const short* __restrict__ A,
    const short* __restrict__ Bt1, const short* __restrict__ Bt2,
    const float* __restrict__ b1, const float* __restrict__ b2,
    short* __restrict__ ff){
  __shared__ short As[128*64];
  __shared__ short B1s[64*64];
  __shared__ short B2s[64*64];
  int t = threadIdx.x, lane = t & 63, w = t >> 6;
  int wr = (w >> 1) * 64, wc = (w & 1) * 32;
  int col0 = blockIdx.x * 64, row0 = blockIdx.y * 128;
  floatx4 a1[4][2], a2[4][2];
  #pragma unroll
  for (int mt=0;mt<4;++mt)
    #pragma unroll
    for (int nt=0;nt<2;++nt){
      a1[mt][nt] = (floatx4){0.f,0.f,0.f,0.f};
      a2[mt][nt] = (floatx4){0.f,0.f,0.f,0.f};
    }
  for (int k0 = 0; k0 < D_; k0 += 64){
    __syncthreads();
    stageG<128,64>(As, A + (size_t)row0*D_ + k0, D_, t);
    stageG<64,64>(B1s, Bt1 + (size_t)col0*D_ + k0, D_, t);
    stageG<64,64>(B2s, Bt2 + (size_t)col0*D_ + k0, D_, t);
    __syncthreads();
    #pragma unroll
    for (int kk = 0; kk < 64; kk += 32){
      short8 af[4], f1[2], f2[2];
      #pragma unroll
      for (int mt=0;mt<4;++mt) af[mt] = fragS(As, 64, wr+mt*16, lane, kk);
      #pragma unroll
      for (int nt=0;nt<2;++nt){
        f1[nt] = fragS(B1s, 64, wc+nt*16, lane, kk);
        f2[nt] = fragS(B2s, 64, wc+nt*16, lane, kk);
      }
      #pragma unroll
      for (int mt=0;mt<4;++mt)
        #pragma unroll
        for (int nt=0;nt<2;++nt){
          a1[mt][nt] = MFMA16(af[mt], f1[nt], a1[mt][nt]);
          a2[mt][nt] = MFMA16(af[mt], f2[nt], a2[mt][nt]);
        }
    }
  }
  int quad = lane >> 4, c = lane & 15;
  #pragma unroll
  for (int mt=0;mt<4;++mt){
    #pragma unroll
    for (int nt=0;nt<2;++nt){
      #pragma unroll
      for (int r=0;r<4;++r){
        int row = row0 + wr + mt*16 + quad*4 + r;
        int col = col0 + wc + nt*16 + c;
        float g1 = a1[mt][nt][r] + (col < HID_ ? b1[col] : 0.f);
        float g2 = a2[mt][nt][r] + (col < HID_ ? b2[col] : 0.f);
        float sig = 1.f / (1.f + __expf(-g1));
        ff[(size_t)row*HIDP + swz(col, row)] = sh(g1*sig*g2);
      }
    }
  }
}

// ---------------- MFMA flash attention, swapped-QK^T, in-register softmax ----------------
// 256 threads = 4 waves, one per 32 q-rows, each covering all 128 keys (best measured).
#define EXP2SC 0.18033688011112042f   // 0.125 * log2(e)
__global__ __launch_bounds__(256) void attn_mfma(
    const short* __restrict__ qb, const short* __restrict__ kbuf,
    const short* __restrict__ vbt, const float* __restrict__ tv,
    short* __restrict__ o){
  __shared__ short Ks2[2][128*64];        // [key][hd] swizzled
  __shared__ short Vt2[2][64*128];        // [hd][key] swizzled
  __shared__ __align__(16) float tsAll[2048];  // tv row (pre-scaled by log2e)
  int qt = blockIdx.x, h = blockIdx.y, b = blockIdx.z;
  int bh = b*H_ + h;
  int t = threadIdx.x, lane = t & 63, w = t >> 6;
  int quad = lane >> 4, c = lane & 15;
  const short* Kbase = kbuf + (size_t)bh*N_*DH_;
  const short* Vbase = vbt  + (size_t)bh*DH_*N_;

  #pragma unroll
  for (int i = 0; i < 2; ++i)
    *(floatx4*)&tsAll[t*8 + i*4] = *(const floatx4*)&tv[(size_t)bh*N_ + t*8 + i*4];
  // stage Q into buffer 1; stage kt=0 K/V into buffer 0
  stageG<128,64>(Ks2[1], qb + ((size_t)bh*N_ + qt*128)*DH_, DH_, t);
  stageG<128,64>(Ks2[0], Kbase, DH_, t);
  stageG<64,128>(Vt2[0], Vbase, N_, t);
  __syncthreads();
  short8 qf[2][2];
  #pragma unroll
  for (int mt=0;mt<2;++mt)
    #pragma unroll
    for (int kh=0;kh<2;++kh)
      qf[mt][kh] = fragS(Ks2[1], 64, w*32 + mt*16, lane, kh*32);
  floatx4 O[2][4];
  float l_i[2] = {0.f, 0.f};
  #pragma unroll
  for (int mt=0;mt<2;++mt)
    #pragma unroll
    for (int nt=0;nt<4;++nt) O[mt][nt] = (floatx4){0.f,0.f,0.f,0.f};
  __syncthreads();   // all waves finished reading Q before buffer 1 is restaged

  for (int kt = 0; kt < N_/128; ++kt){
    int cur = kt & 1;
    if (kt + 1 < N_/128){   // issue next-tile stage; overlaps this tile's compute
      stageG<128,64>(Ks2[cur^1], Kbase + (size_t)(kt+1)*128*DH_, DH_, t);
      stageG<64,128>(Vt2[cur^1], Vbase + (kt+1)*128, N_, t);
    }
    const short* Kc  = Ks2[cur];
    const short* Vc  = Vt2[cur];
    const float* tsc = tsAll + kt*128;
    #pragma unroll
    for (int kb4 = 0; kb4 < 4; ++kb4){     // 32-key sub-blocks
      floatx4 St[2][2];
      #pragma unroll
      for (int i=0;i<2;++i){
        St[i][0] = (floatx4){0.f,0.f,0.f,0.f};
        St[i][1] = (floatx4){0.f,0.f,0.f,0.f};
      }
      #pragma unroll
      for (int kh=0;kh<2;++kh){
        short8 kf0 = fragS(Kc, 64, kb4*32,      lane, kh*32);
        short8 kf1 = fragS(Kc, 64, kb4*32 + 16, lane, kh*32);
        #pragma unroll
        for (int mt=0;mt<2;++mt){
          St[0][mt] = MFMA16(kf0, qf[mt][kh], St[0][mt]);   // C[key][q]
          St[1][mt] = MFMA16(kf1, qf[mt][kh], St[1][mt]);
        }
      }
      floatx4 t0 = *(const floatx4*)&tsc[kb4*32 + quad*4];
      floatx4 t1 = *(const floatx4*)&tsc[kb4*32 + 16 + quad*4];
      short8 pbf[2];
      #pragma unroll
      for (int mt=0;mt<2;++mt){
        float p0[4], p1[4];
        #pragma unroll
        for (int r=0;r<4;++r){
          p0[r] = __builtin_amdgcn_exp2f(fmaf(St[0][mt][r], EXP2SC, -t0[r]));
          p1[r] = __builtin_amdgcn_exp2f(fmaf(St[1][mt][r], EXP2SC, -t1[r]));
        }
        l_i[mt] += (p0[0]+p0[1]) + (p0[2]+p0[3]) + (p1[0]+p1[1]) + (p1[2]+p1[3]);
        // pack consecutive-key pairs, then quad-regroup to the B-fragment layout
        unsigned X0 = pk2(p0[0], p0[1]), X1 = pk2(p0[2], p0[3]);
        unsigned Y0 = pk2(p1[0], p1[1]), Y1 = pk2(p1[2], p1[3]);
        auto u0 = __builtin_amdgcn_permlane32_swap(X0, Y0, false, false);
        auto v0 = __builtin_amdgcn_permlane16_swap(u0[0], u0[1], false, false);
        auto u1 = __builtin_amdgcn_permlane32_swap(X1, Y1, false, false);
        auto v1 = __builtin_amdgcn_permlane16_swap(u1[0], u1[1], false, false);
        union { short8 s; unsigned uu[4]; } pb;
        pb.uu[0] = v0[0]; pb.uu[1] = v1[0]; pb.uu[2] = v0[1]; pb.uu[3] = v1[1];
        pbf[mt] = pb.s;
      }
      // O^T += V^T · P^T   (C[d][q])
      #pragma unroll
      for (int nt=0;nt<4;++nt){
        short8 vf = fragS(Vc, 128, nt*16, lane, kb4*32);
        #pragma unroll
        for (int mt=0;mt<2;++mt)
          O[mt][nt] = MFMA16(vf, pbf[mt], O[mt][nt]);
      }
    }
    __syncthreads();
  }
  // reduce l over quads (keys spread across quads+regs); lane&15 = q
  #pragma unroll
  for (int mt=0;mt<2;++mt){
    float l = l_i[mt];
    l += __shfl_xor(l, 16, 64);
    l += __shfl_xor(l, 32, 64);
    float invl = 1.f / l;
    int qrow = qt*128 + w*32 + mt*16 + c;
    size_t rb = ((size_t)b*N_ + qrow)*(size_t)D_;
    #pragma unroll
    for (int nt=0;nt<4;++nt){
      int d0 = h*DH_ + nt*16 + quad*4;     // 4 consecutive d per lane
      uint2v pv;
      pv.x = pk2(O[mt][nt][0]*invl, O[mt][nt][1]*invl);
      pv.y = pk2(O[mt][nt][2]*invl, O[mt][nt][3]*invl);
      *(uint2v*)(o + rb + swz(d0, qrow)) = pv;   // swz keeps 4-short runs intact
    }
  }
}

extern "C" void kernel_launch(void* const* d_in, const int* in_sizes, int n_in,
                              void* d_out, int out_size, void* d_ws, size_t ws_size,
                              hipStream_t stream){
  const float* x      = (const float*)d_in[0];
  const float* coords = (const float*)d_in[1];
  const float* ln1_w  = (const float*)d_in[2];
  const float* ln1_b  = (const float*)d_in[3];
  const float* ln2_w  = (const float*)d_in[4];
  const float* ln2_b  = (const float*)d_in[5];
  const float* Wqkv   = (const float*)d_in[6];
  const float* bqkv   = (const float*)d_in[7];
  const float* Wo     = (const float*)d_in[8];
  const float* bo     = (const float*)d_in[9];
  const float* Wc     = (const float*)d_in[10];
  // d_in[11] = bc: constant over softmax axis -> no effect on output
  const float* W1     = (const float*)d_in[12];
  const float* b1     = (const float*)d_in[13];
  const float* W2     = (const float*)d_in[14];
  const float* b2     = (const float*)d_in[15];
  const float* W3     = (const float*)d_in[16];
  const float* b3     = (const float*)d_in[17];

  // ws layout (peak 40.2 MB), all bf16 raw shorts; swizzled layouts as documented
  char* ws = (char*)d_ws;
  short* Wtqkv = (short*)(ws);                         // [1536][512]
  short* Wto   = (short*)(ws + 1572864);               // [512][512]
  short* Wt1   = (short*)(ws + 2097152);               // [1408][512]
  short* Wt2   = (short*)(ws + 3538944);               // [1408][512]
  short* Wt3   = (short*)(ws + 4980736);               // [512][1408]
  float* tv    = (float*)(ws + 6422528);               // [32][2048]
  short* h     = (short*)(ws + 6684672);               // [8192][512]
  short* qb    = (short*)(ws + 15073280);              // 8 MB
  short* kb    = (short*)(ws + 23461888);              // 8 MB
  short* vbt   = (short*)(ws + 31850496);              // 8 MB  [bh][hd][n]
  short* o     = h;                                    // alias: h dead after qkv
  short* h2    = h;                                    // alias: o dead after wo
  short* ff    = qb;                                   // alias: q/k/v dead after attn
  float* x1    = (float*)d_out;                        // f32 [8192][512] = d_out

  // blocks: [0,3136) weights, [3136,3392) coord proj, [3392,11584) LN1
  convT_all<<<dim3(11584), dim3(256), 0, stream>>>(Wqkv, Wo, W1, W2, W3,
      Wtqkv, Wto, Wt1, Wt2, Wt3, coords, Wc, tv, x, ln1_w, ln1_b, h);
  qkv_gemm<<<dim3(12,64), dim3(256), 0, stream>>>(h, Wtqkv, bqkv, qb, kb, vbt);
  attn_mfma<<<dim3(16,8,4), dim3(256), 0, stream>>>(qb, kb, vbt, tv, o);
  gemm64<<<dim3(8,64), dim3(256), 0, stream>>>(o, 512, Wto, 512, bo, x, x1);
  ln_kernel<<<dim3(ROWS_), dim3(256), 0, stream>>>(x1, ln2_w, ln2_b, h2);
  gate_gemm<<<dim3(22,64), dim3(256), 0, stream>>>(h2, Wt1, Wt2, b1, b2, ff);
  gemm64<<<dim3(8,64), dim3(256), 0, stream>>>(ff, HIDP, Wt3, HIDP, b3, x1, x1);
}

// Round 5
// 305.120 us; speedup vs baseline: 1.1802x; 1.0277x over previous
//
#include <hip/hip_runtime.h>
#include <hip/hip_bf16.h>
#include <math.h>

#define B_   4
#define N_   2048
#define D_   512
#define H_   8
#define DH_  64
#define C_   3
#define HID_ 1365
#define HIDP 1408          // padded HID (11 * 128)
#define ROWS_ (B_*N_)      // 8192
#define TD_  (3*D_)        // 1536

typedef __attribute__((ext_vector_type(8))) short short8;   // 8 bf16 = 4 VGPR
typedef __attribute__((ext_vector_type(4))) float floatx4;
typedef __attribute__((ext_vector_type(2))) unsigned uint2v;

#define MFMA16(a,b,c) __builtin_amdgcn_mfma_f32_16x16x32_bf16(a,b,c,0,0,0)

typedef __attribute__((address_space(3))) unsigned lds_u32;
typedef __attribute__((address_space(1))) unsigned glb_u32;

__device__ __forceinline__ short sh(float v){
  union { __hip_bfloat16 b; short s; } u;
  u.b = __float2bfloat16(v);
  return u.s;
}

// pack two floats into one u32 of 2 bf16 (low = a); compiler fuses to cvt_pk
__device__ __forceinline__ unsigned pk2(float a, float b){
  union { short s[2]; unsigned u; } z;
  z.s[0] = sh(a); z.s[1] = sh(b);
  return z.u;
}

// global-layout segment swizzle: within each 64-short k-block, 16B segment s -> s ^ (row&7)
__device__ __forceinline__ int swz(int col, int row){
  return (col & ~63) | (col & 7) | ((((col >> 3) & 7) ^ (row & 7)) << 3);
}

// async global->LDS stage: ROWS rows of PITCH shorts (16B-swizzled global layout assumed).
template<int ROWS, int PITCH, int WAVES = 4>
__device__ __forceinline__ void stageG(short* __restrict__ lds,
    const short* __restrict__ g, int ldg, int t){
  const int LPR = PITCH/8;          // lanes per row
  const int RPI = 64/LPR;           // rows per instruction
  const int PW  = (ROWS/RPI)/WAVES; // instructions per wave
  int lane = t & 63, w = t >> 6;
  #pragma unroll
  for (int i = 0; i < PW; ++i){
    int r0  = (w*PW + i)*RPI;
    int row = r0 + lane/LPR;
    const short* ga = g + (size_t)row*ldg + (lane % LPR)*8;
    short* la = lds + r0*PITCH;     // wave-uniform; HW adds lane*16B
    __builtin_amdgcn_global_load_lds((const glb_u32*)ga, (lds_u32*)la, 16, 0, 0);
  }
}

// MFMA fragment from unpadded swizzled LDS tile
__device__ __forceinline__ short8 fragS(const short* __restrict__ lds, int pitch,
    int mbase, int lane, int kk){
  int row  = mbase + (lane & 15);
  int seg  = (kk >> 3) + (lane >> 4);
  int phys = seg ^ (row & 7);
  return *(const short8*)(lds + row*pitch + phys*8);
}

// ---------------- merged: weight transpose-convert (swizzled) + coord proj + LN1 ----------------
__global__ __launch_bounds__(256) void convT_all(
    const float* __restrict__ Wqkv, const float* __restrict__ Wo,
    const float* __restrict__ W1, const float* __restrict__ W2,
    const float* __restrict__ W3,
    short* __restrict__ Wtqkv, short* __restrict__ Wto,
    short* __restrict__ Wt1, short* __restrict__ Wt2, short* __restrict__ Wt3,
    const float* __restrict__ coords, const float* __restrict__ Wc,
    float* __restrict__ tv,
    const float* __restrict__ x, const float* __restrict__ ln1_w,
    const float* __restrict__ ln1_b, short* __restrict__ h){
  int id = blockIdx.x;
  int t = threadIdx.x;
  if (id >= 3392){            // ---- LN1 rows (float2 loads, packed u32 store) ----
    int row = id - 3392;
    size_t base = (size_t)row * D_;
    float2 u = *(const float2*)&x[base + 2*t];
    float s  = u.x + u.y;
    float s2 = u.x*u.x + u.y*u.y;
    #pragma unroll
    for (int off = 32; off >= 1; off >>= 1){
      s  += __shfl_xor(s,  off, 64);
      s2 += __shfl_xor(s2, off, 64);
    }
    __shared__ float red[8];
    int lane = t & 63, wv = t >> 6;
    if (lane == 0){ red[wv] = s; red[4+wv] = s2; }
    __syncthreads();
    float sum  = red[0]+red[1]+red[2]+red[3];
    float sum2 = red[4]+red[5]+red[6]+red[7];
    float mean = sum * (1.0f/D_);
    float var  = sum2 * (1.0f/D_) - mean*mean;
    float inv  = rsqrtf(fmaxf(var, 0.f) + 1e-5f);
    float2 wv2 = *(const float2*)&ln1_w[2*t];
    float2 bv2 = *(const float2*)&ln1_b[2*t];
    *(unsigned*)(h + base + swz(2*t, row)) =
        pk2((u.x-mean)*inv*wv2.x + bv2.x, (u.y-mean)*inv*wv2.y + bv2.y);
    return;
  }
  if (id >= 3136){            // ---- coord projection: tv = coords·Wc * log2(e) ----
    int idx = (id - 3136)*256 + t;
    int n = idx & (N_-1);
    int hh = (idx >> 11) & (H_-1);
    int b = idx >> 14;
    float s = 0.f;
    #pragma unroll
    for (int cc = 0; cc < C_; ++cc)
      s += coords[((size_t)(b*N_+n))*C_ + cc] * Wc[cc*H_ + hh];
    tv[idx] = s * 1.44269504f;       // pre-scaled into exp2 domain
    return;
  }
  // ---- weight transpose-convert ----
  __shared__ float tile[32][33];
  const float* in; short* out; int K, NN, Kp, nx;
  if (id < 768)      { in=Wqkv; out=Wtqkv; K=512;  NN=1536; Kp=512;  nx=48; }
  else if (id < 1024){ in=Wo;   out=Wto;   K=512;  NN=512;  Kp=512;  nx=16; id-=768; }
  else if (id < 1728){ in=W1;   out=Wt1;   K=512;  NN=HID_; Kp=512;  nx=44; id-=1024; }
  else if (id < 2432){ in=W2;   out=Wt2;   K=512;  NN=HID_; Kp=512;  nx=44; id-=1728; }
  else               { in=W3;   out=Wt3;   K=HID_; NN=512;  Kp=HIDP; nx=16; id-=2432; }
  int nt0 = (id % nx)*32, kt0 = (id / nx)*32;
  int r = t >> 5, cc = t & 31;
  #pragma unroll
  for (int i=0;i<4;++i){
    int k = kt0 + i*8 + r, n = nt0 + cc;
    tile[i*8+r][cc] = (k<K && n<NN) ? in[(size_t)k*NN + n] : 0.f;
  }
  __syncthreads();
  #pragma unroll
  for (int i=0;i<4;++i){
    int n = nt0 + i*8 + r, k = kt0 + cc;
    out[(size_t)n*Kp + swz(k, n)] = sh(tile[cc][i*8+r]);
  }
}

// ---------------- LayerNorm (f32 in, swizzled bf16 out); float2 loads, u32 store ----------------
__global__ __launch_bounds__(256) void ln_kernel(const float* __restrict__ x,
        const float* __restrict__ w, const float* __restrict__ b,
        short* __restrict__ out){
  int row = blockIdx.x;
  size_t base = (size_t)row * D_;
  int t = threadIdx.x;
  float2 u = *(const float2*)&x[base + 2*t];
  float s  = u.x + u.y;
  float s2 = u.x*u.x + u.y*u.y;
  #pragma unroll
  for (int off = 32; off >= 1; off >>= 1){
    s  += __shfl_xor(s,  off, 64);
    s2 += __shfl_xor(s2, off, 64);
  }
  __shared__ float red[8];
  int lane = t & 63, wv = t >> 6;
  if (lane == 0){ red[wv] = s; red[4+wv] = s2; }
  __syncthreads();
  float sum  = red[0]+red[1]+red[2]+red[3];
  float sum2 = red[4]+red[5]+red[6]+red[7];
  float mean = sum * (1.0f/D_);
  float var  = sum2 * (1.0f/D_) - mean*mean;
  float inv  = rsqrtf(fmaxf(var, 0.f) + 1e-5f);
  float2 wv2 = *(const float2*)&w[2*t];
  float2 bv2 = *(const float2*)&b[2*t];
  *(unsigned*)(out + base + swz(2*t, row)) =
      pk2((u.x-mean)*inv*wv2.x + bv2.x, (u.y-mean)*inv*wv2.y + bv2.y);
}

// ---------------- QKV GEMM 128x128, dbuf; q/k swapped-orientation packed epilogue ----------------
__global__ __launch_bounds__(256) void qkv_gemm(
    const short* __restrict__ A, const short* __restrict__ Bt,
    const float* __restrict__ bias,
    short* __restrict__ qb, short* __restrict__ kb, short* __restrict__ vbt){
  __shared__ short As[2][128*64];
  __shared__ short Bs[2][128*64];
  int t = threadIdx.x;
  int lane = t & 63, w = t >> 6;
  int wr = (w >> 1) * 64, wc = (w & 1) * 64;
  int col0 = blockIdx.x * 128, row0 = blockIdx.y * 128;
  bool vblk = (blockIdx.x >= 8);        // v cols 1024..1535
  floatx4 acc[4][4];
  #pragma unroll
  for (int mt=0;mt<4;++mt)
    #pragma unroll
    for (int nt=0;nt<4;++nt) acc[mt][nt] = (floatx4){0.f,0.f,0.f,0.f};
  stageG<128,64>(As[0], A  + (size_t)row0*D_, D_, t);
  stageG<128,64>(Bs[0], Bt + (size_t)col0*D_, D_, t);
  for (int ti = 0; ti < 8; ++ti){
    int cur = ti & 1;
    __syncthreads();
    if (ti + 1 < 8){
      stageG<128,64>(As[cur^1], A  + (size_t)row0*D_ + (ti+1)*64, D_, t);
      stageG<128,64>(Bs[cur^1], Bt + (size_t)col0*D_ + (ti+1)*64, D_, t);
    }
    #pragma unroll
    for (int kk = 0; kk < 64; kk += 32){
      short8 af[4], bf[4];
      #pragma unroll
      for (int mt=0;mt<4;++mt) af[mt] = fragS(As[cur], 64, wr+mt*16, lane, kk);
      #pragma unroll
      for (int nt=0;nt<4;++nt) bf[nt] = fragS(Bs[cur], 64, wc+nt*16, lane, kk);
      if (vblk){
        #pragma unroll
        for (int mt=0;mt<4;++mt)
          #pragma unroll
          for (int nt=0;nt<4;++nt)
            acc[mt][nt] = MFMA16(af[mt], bf[nt], acc[mt][nt]);   // regs=rows, lanes=cols
      } else {
        #pragma unroll
        for (int mt=0;mt<4;++mt)
          #pragma unroll
          for (int nt=0;nt<4;++nt)
            acc[mt][nt] = MFMA16(bf[nt], af[mt], acc[mt][nt]);   // regs=cols, lanes=rows
      }
    }
  }
  int quad = lane >> 4, c = lane & 15;
  if (vblk){
    // normal orientation: lane = col (d), regs = 4 consecutive rows (n) -> pack along n
    #pragma unroll
    for (int mt=0;mt<4;++mt){
      int rb0 = row0 + wr + mt*16 + quad*4;     // 4 consecutive rows, 4-aligned
      int bidx = rb0 >> 11, n0 = rb0 & (N_-1);
      #pragma unroll
      for (int nt=0;nt<4;++nt){
        int col = col0 + wc + nt*16 + c;
        int d = col & (D_-1), hh = d >> 6, hd = d & 63;
        float bc = bias[col];
        uint2v pv;
        pv.x = pk2(acc[mt][nt][0]+bc, acc[mt][nt][1]+bc);
        pv.y = pk2(acc[mt][nt][2]+bc, acc[mt][nt][3]+bc);
        *(uint2v*)(vbt + (((size_t)(bidx*H_ + hh))*DH_ + hd)*N_ + swz(n0, hd)) = pv;
      }
    }
  } else {
    // swapped orientation: lane = row (n), regs = 4 consecutive cols (d) -> pack along d
    #pragma unroll
    for (int mt=0;mt<4;++mt){
      int row = row0 + wr + mt*16 + c;
      int bidx = row >> 11, n = row & (N_-1);
      #pragma unroll
      for (int nt=0;nt<4;++nt){
        int d0 = col0 + wc + nt*16 + quad*4;    // 4 consecutive cols, 4-aligned
        floatx4 b4 = *(const floatx4*)&bias[d0];
        int which = d0 >> 9, dd = d0 & (D_-1), hh = dd >> 6, hd0 = dd & 63;
        short* dst = which ? kb : qb;
        uint2v pv;
        pv.x = pk2(acc[mt][nt][0]+b4[0], acc[mt][nt][1]+b4[1]);
        pv.y = pk2(acc[mt][nt][2]+b4[2], acc[mt][nt][3]+b4[3]);
        *(uint2v*)(dst + (((size_t)(bidx*H_ + hh))*N_ + n)*DH_ + swz(hd0, n)) = pv;
      }
    }
  }
}

// ---------------- MFMA GEMM 128x64, dbuf, swapped orientation, float4 epilogue ----------------
__global__ __launch_bounds__(256) void gemm64(
    const short* __restrict__ A, int lda,
    const short* __restrict__ Bt, int Ktot,
    const float* __restrict__ bias,
    const float* __restrict__ resid, float* __restrict__ outF){
  __shared__ short As[2][128*64];
  __shared__ short Bs[2][64*64];
  int t = threadIdx.x, lane = t & 63, w = t >> 6;
  int wr = w * 32;
  int col0 = blockIdx.x * 64, row0 = blockIdx.y * 128;
  floatx4 acc[2][4];
  #pragma unroll
  for (int mt=0;mt<2;++mt)
    #pragma unroll
    for (int nt=0;nt<4;++nt) acc[mt][nt] = (floatx4){0.f,0.f,0.f,0.f};
  stageG<128,64>(As[0], A  + (size_t)row0*lda, lda, t);
  stageG<64,64> (Bs[0], Bt + (size_t)col0*Ktot, Ktot, t);
  const int NT = Ktot >> 6;
  for (int ti = 0; ti < NT; ++ti){
    int cur = ti & 1;
    __syncthreads();
    if (ti + 1 < NT){
      stageG<128,64>(As[cur^1], A  + (size_t)row0*lda + (ti+1)*64, lda, t);
      stageG<64,64> (Bs[cur^1], Bt + (size_t)col0*Ktot + (ti+1)*64, Ktot, t);
    }
    #pragma unroll
    for (int kk = 0; kk < 64; kk += 32){
      short8 af[2], bf[4];
      #pragma unroll
      for (int mt=0;mt<2;++mt) af[mt] = fragS(As[cur], 64, wr+mt*16, lane, kk);
      #pragma unroll
      for (int nt=0;nt<4;++nt) bf[nt] = fragS(Bs[cur], 64, nt*16, lane, kk);
      #pragma unroll
      for (int mt=0;mt<2;++mt)
        #pragma unroll
        for (int nt=0;nt<4;++nt)
          acc[mt][nt] = MFMA16(bf[nt], af[mt], acc[mt][nt]);   // swapped: regs=cols
    }
  }
  int quad = lane >> 4, c = lane & 15;
  #pragma unroll
  for (int mt=0;mt<2;++mt){
    int row = row0 + wr + mt*16 + c;
    #pragma unroll
    for (int nt=0;nt<4;++nt){
      int c0 = col0 + nt*16 + quad*4;           // 4 consecutive cols
      size_t idx = (size_t)row*D_ + c0;
      float4 rv = *(const float4*)&resid[idx];
      floatx4 b4 = *(const floatx4*)&bias[c0];
      float4 ov;
      ov.x = acc[mt][nt][0] + b4[0] + rv.x;
      ov.y = acc[mt][nt][1] + b4[1] + rv.y;
      ov.z = acc[mt][nt][2] + b4[2] + rv.z;
      ov.w = acc[mt][nt][3] + b4[3] + rv.w;
      *(float4*)&outF[idx] = ov;
    }
  }
}

// ---------------- fused SwiGLU gate GEMM: 128x64, dual-B, swapped, packed stores ----------------
__global__ __launch_bounds__(256) void gate_gemm(
    const short* __restrict__ A,
    const short* __restrict__ Bt1, const short* __restrict__ Bt2,
    const float* __restrict__ b1, const float* __restrict__ b2,
    short* __restrict__ ff){
  __shared__ short As[128*64];
  __shared__ short B1s[64*64];
  __shared__ short B2s[64*64];
  int t = threadIdx.x, lane = t & 63, w = t >> 6;
  int wr = (w >> 1) * 64, wc = (w & 1) * 32;
  int col0 = blockIdx.x * 64, row0 = blockIdx.y * 128;
  floatx4 a1[4][2], a2[4][2];
  #pragma unroll
  for (int mt=0;mt<4;++mt)
    #pragma unroll
    for (int nt=0;nt<2;++nt){
      a1[mt][nt] = (floatx4){0.f,0.f,0.f,0.f};
      a2[mt][nt] = (floatx4){0.f,0.f,0.f,0.f};
    }
  for (int k0 = 0; k0 < D_; k0 += 64){
    __syncthreads();
    stageG<128,64>(As, A + (size_t)row0*D_ + k0, D_, t);
    stageG<64,64>(B1s, Bt1 + (size_t)col0*D_ + k0, D_, t);
    stageG<64,64>(B2s, Bt2 + (size_t)col0*D_ + k0, D_, t);
    __syncthreads();
    #pragma unroll
    for (int kk = 0; kk < 64; kk += 32){
      short8 af[4], f1[2], f2[2];
      #pragma unroll
      for (int mt=0;mt<4;++mt) af[mt] = fragS(As, 64, wr+mt*16, lane, kk);
      #pragma unroll
      for (int nt=0;nt<2;++nt){
        f1[nt] = fragS(B1s, 64, wc+nt*16, lane, kk);
        f2[nt] = fragS(B2s, 64, wc+nt*16, lane, kk);
      }
      #pragma unroll
      for (int mt=0;mt<4;++mt)
        #pragma unroll
        for (int nt=0;nt<2;++nt){
          a1[mt][nt] = MFMA16(f1[nt], af[mt], a1[mt][nt]);   // swapped: regs=cols
          a2[mt][nt] = MFMA16(f2[nt], af[mt], a2[mt][nt]);
        }
    }
  }
  int quad = lane >> 4, c = lane & 15;
  #pragma unroll
  for (int mt=0;mt<4;++mt){
    int row = row0 + wr + mt*16 + c;
    size_t rbase = (size_t)row * HIDP;
    #pragma unroll
    for (int nt=0;nt<2;++nt){
      int c0 = col0 + wc + nt*16 + quad*4;      // 4 consecutive cols
      float v[4];
      #pragma unroll
      for (int r=0;r<4;++r){
        int col = c0 + r;
        float g1 = a1[mt][nt][r] + (col < HID_ ? b1[col] : 0.f);
        float g2 = a2[mt][nt][r] + (col < HID_ ? b2[col] : 0.f);
        float sig = 1.f / (1.f + __expf(-g1));
        v[r] = g1*sig*g2;
      }
      uint2v pv;
      pv.x = pk2(v[0], v[1]);
      pv.y = pk2(v[2], v[3]);
      *(uint2v*)(ff + rbase + swz(c0, row)) = pv;
    }
  }
}

// ---------------- MFMA flash attention, swapped-QK^T, in-register softmax ----------------
// 256 threads = 4 waves, one per 32 q-rows, each covering all 128 keys (best measured).
#define EXP2SC 0.18033688011112042f   // 0.125 * log2(e)
__global__ __launch_bounds__(256) void attn_mfma(
    const short* __restrict__ qb, const short* __restrict__ kbuf,
    const short* __restrict__ vbt, const float* __restrict__ tv,
    short* __restrict__ o){
  __shared__ short Ks2[2][128*64];        // [key][hd] swizzled
  __shared__ short Vt2[2][64*128];        // [hd][key] swizzled
  __shared__ __align__(16) float tsAll[2048];  // tv row (pre-scaled by log2e)
  int qt = blockIdx.x, h = blockIdx.y, b = blockIdx.z;
  int bh = b*H_ + h;
  int t = threadIdx.x, lane = t & 63, w = t >> 6;
  int quad = lane >> 4, c = lane & 15;
  const short* Kbase = kbuf + (size_t)bh*N_*DH_;
  const short* Vbase = vbt  + (size_t)bh*DH_*N_;

  #pragma unroll
  for (int i = 0; i < 2; ++i)
    *(floatx4*)&tsAll[t*8 + i*4] = *(const floatx4*)&tv[(size_t)bh*N_ + t*8 + i*4];
  // stage Q into buffer 1; stage kt=0 K/V into buffer 0
  stageG<128,64>(Ks2[1], qb + ((size_t)bh*N_ + qt*128)*DH_, DH_, t);
  stageG<128,64>(Ks2[0], Kbase, DH_, t);
  stageG<64,128>(Vt2[0], Vbase, N_, t);
  __syncthreads();
  short8 qf[2][2];
  #pragma unroll
  for (int mt=0;mt<2;++mt)
    #pragma unroll
    for (int kh=0;kh<2;++kh)
      qf[mt][kh] = fragS(Ks2[1], 64, w*32 + mt*16, lane, kh*32);
  floatx4 O[2][4];
  float l_i[2] = {0.f, 0.f};
  #pragma unroll
  for (int mt=0;mt<2;++mt)
    #pragma unroll
    for (int nt=0;nt<4;++nt) O[mt][nt] = (floatx4){0.f,0.f,0.f,0.f};
  __syncthreads();   // all waves finished reading Q before buffer 1 is restaged

  for (int kt = 0; kt < N_/128; ++kt){
    int cur = kt & 1;
    if (kt + 1 < N_/128){   // issue next-tile stage; overlaps this tile's compute
      stageG<128,64>(Ks2[cur^1], Kbase + (size_t)(kt+1)*128*DH_, DH_, t);
      stageG<64,128>(Vt2[cur^1], Vbase + (kt+1)*128, N_, t);
    }
    const short* Kc  = Ks2[cur];
    const short* Vc  = Vt2[cur];
    const float* tsc = tsAll + kt*128;
    #pragma unroll
    for (int kb4 = 0; kb4 < 4; ++kb4){     // 32-key sub-blocks
      floatx4 St[2][2];
      #pragma unroll
      for (int i=0;i<2;++i){
        St[i][0] = (floatx4){0.f,0.f,0.f,0.f};
        St[i][1] = (floatx4){0.f,0.f,0.f,0.f};
      }
      #pragma unroll
      for (int kh=0;kh<2;++kh){
        short8 kf0 = fragS(Kc, 64, kb4*32,      lane, kh*32);
        short8 kf1 = fragS(Kc, 64, kb4*32 + 16, lane, kh*32);
        #pragma unroll
        for (int mt=0;mt<2;++mt){
          St[0][mt] = MFMA16(kf0, qf[mt][kh], St[0][mt]);   // C[key][q]
          St[1][mt] = MFMA16(kf1, qf[mt][kh], St[1][mt]);
        }
      }
      floatx4 t0 = *(const floatx4*)&tsc[kb4*32 + quad*4];
      floatx4 t1 = *(const floatx4*)&tsc[kb4*32 + 16 + quad*4];
      short8 pbf[2];
      #pragma unroll
      for (int mt=0;mt<2;++mt){
        float p0[4], p1[4];
        #pragma unroll
        for (int r=0;r<4;++r){
          p0[r] = __builtin_amdgcn_exp2f(fmaf(St[0][mt][r], EXP2SC, -t0[r]));
          p1[r] = __builtin_amdgcn_exp2f(fmaf(St[1][mt][r], EXP2SC, -t1[r]));
        }
        l_i[mt] += (p0[0]+p0[1]) + (p0[2]+p0[3]) + (p1[0]+p1[1]) + (p1[2]+p1[3]);
        // pack consecutive-key pairs, then quad-regroup to the B-fragment layout
        unsigned X0 = pk2(p0[0], p0[1]), X1 = pk2(p0[2], p0[3]);
        unsigned Y0 = pk2(p1[0], p1[1]), Y1 = pk2(p1[2], p1[3]);
        auto u0 = __builtin_amdgcn_permlane32_swap(X0, Y0, false, false);
        auto v0 = __builtin_amdgcn_permlane16_swap(u0[0], u0[1], false, false);
        auto u1 = __builtin_amdgcn_permlane32_swap(X1, Y1, false, false);
        auto v1 = __builtin_amdgcn_permlane16_swap(u1[0], u1[1], false, false);
        union { short8 s; unsigned uu[4]; } pb;
        pb.uu[0] = v0[0]; pb.uu[1] = v1[0]; pb.uu[2] = v0[1]; pb.uu[3] = v1[1];
        pbf[mt] = pb.s;
      }
      // O^T += V^T · P^T   (C[d][q])
      #pragma unroll
      for (int nt=0;nt<4;++nt){
        short8 vf = fragS(Vc, 128, nt*16, lane, kb4*32);
        #pragma unroll
        for (int mt=0;mt<2;++mt)
          O[mt][nt] = MFMA16(vf, pbf[mt], O[mt][nt]);
      }
    }
    __syncthreads();
  }
  // reduce l over quads (keys spread across quads+regs); lane&15 = q
  #pragma unroll
  for (int mt=0;mt<2;++mt){
    float l = l_i[mt];
    l += __shfl_xor(l, 16, 64);
    l += __shfl_xor(l, 32, 64);
    float invl = 1.f / l;
    int qrow = qt*128 + w*32 + mt*16 + c;
    size_t rb = ((size_t)b*N_ + qrow)*(size_t)D_;
    #pragma unroll
    for (int nt=0;nt<4;++nt){
      int d0 = h*DH_ + nt*16 + quad*4;     // 4 consecutive d per lane
      uint2v pv;
      pv.x = pk2(O[mt][nt][0]*invl, O[mt][nt][1]*invl);
      pv.y = pk2(O[mt][nt][2]*invl, O[mt][nt][3]*invl);
      *(uint2v*)(o + rb + swz(d0, qrow)) = pv;   // swz keeps 4-short runs intact
    }
  }
}

extern "C" void kernel_launch(void* const* d_in, const int* in_sizes, int n_in,
                              void* d_out, int out_size, void* d_ws, size_t ws_size,
                              hipStream_t stream){
  const float* x      = (const float*)d_in[0];
  const float* coords = (const float*)d_in[1];
  const float* ln1_w  = (const float*)d_in[2];
  const float* ln1_b  = (const float*)d_in[3];
  const float* ln2_w  = (const float*)d_in[4];
  const float* ln2_b  = (const float*)d_in[5];
  const float* Wqkv   = (const float*)d_in[6];
  const float* bqkv   = (const float*)d_in[7];
  const float* Wo     = (const float*)d_in[8];
  const float* bo     = (const float*)d_in[9];
  const float* Wc     = (const float*)d_in[10];
  // d_in[11] = bc: constant over softmax axis -> no effect on output
  const float* W1     = (const float*)d_in[12];
  const float* b1     = (const float*)d_in[13];
  const float* W2     = (const float*)d_in[14];
  const float* b2     = (const float*)d_in[15];
  const float* W3     = (const float*)d_in[16];
  const float* b3     = (const float*)d_in[17];

  // ws layout (peak 40.2 MB), all bf16 raw shorts; swizzled layouts as documented
  char* ws = (char*)d_ws;
  short* Wtqkv = (short*)(ws);                         // [1536][512]
  short* Wto   = (short*)(ws + 1572864);               // [512][512]
  short* Wt1   = (short*)(ws + 2097152);               // [1408][512]
  short* Wt2   = (short*)(ws + 3538944);               // [1408][512]
  short* Wt3   = (short*)(ws + 4980736);               // [512][1408]
  float* tv    = (float*)(ws + 6422528);               // [32][2048]
  short* h     = (short*)(ws + 6684672);               // [8192][512]
  short* qb    = (short*)(ws + 15073280);              // 8 MB
  short* kb    = (short*)(ws + 23461888);              // 8 MB
  short* vbt   = (short*)(ws + 31850496);              // 8 MB  [bh][hd][n]
  short* o     = h;                                    // alias: h dead after qkv
  short* h2    = h;                                    // alias: o dead after wo
  short* ff    = qb;                                   // alias: q/k/v dead after attn
  float* x1    = (float*)d_out;                        // f32 [8192][512] = d_out

  // blocks: [0,3136) weights, [3136,3392) coord proj, [3392,11584) LN1
  convT_all<<<dim3(11584), dim3(256), 0, stream>>>(Wqkv, Wo, W1, W2, W3,
      Wtqkv, Wto, Wt1, Wt2, Wt3, coords, Wc, tv, x, ln1_w, ln1_b, h);
  qkv_gemm<<<dim3(12,64), dim3(256), 0, stream>>>(h, Wtqkv, bqkv, qb, kb, vbt);
  attn_mfma<<<dim3(16,8,4), dim3(256), 0, stream>>>(qb, kb, vbt, tv, o);
  gemm64<<<dim3(8,64), dim3(256), 0, stream>>>(o, 512, Wto, 512, bo, x, x1);
  ln_kernel<<<dim3(ROWS_), dim3(256), 0, stream>>>(x1, ln2_w, ln2_b, h2);
  gate_gemm<<<dim3(22,64), dim3(256), 0, stream>>>(h2, Wt1, Wt2, b1, b2, ff);
  gemm64<<<dim3(8,64), dim3(256), 0, stream>>>(ff, HIDP, Wt3, HIDP, b3, x1, x1);
}

// Round 6
// 277.166 us; speedup vs baseline: 1.2993x; 1.1009x over previous
//
#include <hip/hip_runtime.h>
#include <hip/hip_bf16.h>
#include <math.h>

#define B_   4
#define N_   2048
#define D_   512
#define H_   8
#define DH_  64
#define C_   3
#define HID_ 1365
#define HIDP 1408          // padded HID (11 * 128)
#define ROWS_ (B_*N_)      // 8192
#define TD_  (3*D_)        // 1536

typedef __attribute__((ext_vector_type(8))) short short8;   // 8 bf16 = 4 VGPR
typedef __attribute__((ext_vector_type(4))) float floatx4;
typedef __attribute__((ext_vector_type(2))) unsigned uint2v;

#define MFMA16(a,b,c) __builtin_amdgcn_mfma_f32_16x16x32_bf16(a,b,c,0,0,0)

typedef __attribute__((address_space(3))) unsigned lds_u32;
typedef __attribute__((address_space(1))) unsigned glb_u32;

__device__ __forceinline__ short sh(float v){
  union { __hip_bfloat16 b; short s; } u;
  u.b = __float2bfloat16(v);
  return u.s;
}

// pack two floats into one u32 of 2 bf16 (low = a); compiler fuses to cvt_pk
__device__ __forceinline__ unsigned pk2(float a, float b){
  union { short s[2]; unsigned u; } z;
  z.s[0] = sh(a); z.s[1] = sh(b);
  return z.u;
}

// global-layout segment swizzle: within each 64-short k-block, 16B segment s -> s ^ (row&7)
__device__ __forceinline__ int swz(int col, int row){
  return (col & ~63) | (col & 7) | ((((col >> 3) & 7) ^ (row & 7)) << 3);
}

// XCD-aware bijective block remap (nwg % 8 == 0): consecutive remapped ids stay on one XCD
__device__ __forceinline__ int xcdswz(int bid, int nwg){
  return (bid & 7) * (nwg >> 3) + (bid >> 3);
}

// async global->LDS stage: ROWS rows of PITCH shorts (16B-swizzled global layout assumed).
template<int ROWS, int PITCH, int WAVES = 4>
__device__ __forceinline__ void stageG(short* __restrict__ lds,
    const short* __restrict__ g, int ldg, int t){
  const int LPR = PITCH/8;          // lanes per row
  const int RPI = 64/LPR;           // rows per instruction
  const int PW  = (ROWS/RPI)/WAVES; // instructions per wave
  int lane = t & 63, w = t >> 6;
  #pragma unroll
  for (int i = 0; i < PW; ++i){
    int r0  = (w*PW + i)*RPI;
    int row = r0 + lane/LPR;
    const short* ga = g + (size_t)row*ldg + (lane % LPR)*8;
    short* la = lds + r0*PITCH;     // wave-uniform; HW adds lane*16B
    __builtin_amdgcn_global_load_lds((const glb_u32*)ga, (lds_u32*)la, 16, 0, 0);
  }
}

// MFMA fragment from unpadded swizzled LDS tile
__device__ __forceinline__ short8 fragS(const short* __restrict__ lds, int pitch,
    int mbase, int lane, int kk){
  int row  = mbase + (lane & 15);
  int seg  = (kk >> 3) + (lane >> 4);
  int phys = seg ^ (row & 7);
  return *(const short8*)(lds + row*pitch + phys*8);
}

// ---------------- merged: weight transpose-convert (swizzled) + coord proj + LN1 ----------------
__global__ __launch_bounds__(256) void convT_all(
    const float* __restrict__ Wqkv, const float* __restrict__ Wo,
    const float* __restrict__ W1, const float* __restrict__ W2,
    const float* __restrict__ W3,
    short* __restrict__ Wtqkv, short* __restrict__ Wto,
    short* __restrict__ Wt1, short* __restrict__ Wt2, short* __restrict__ Wt3,
    const float* __restrict__ coords, const float* __restrict__ Wc,
    float* __restrict__ tv,
    const float* __restrict__ x, const float* __restrict__ ln1_w,
    const float* __restrict__ ln1_b, short* __restrict__ h){
  int id = blockIdx.x;
  int t = threadIdx.x;
  if (id >= 3392){            // ---- LN1 rows (float2 loads, packed u32 store) ----
    int row = id - 3392;
    size_t base = (size_t)row * D_;
    float2 u = *(const float2*)&x[base + 2*t];
    float s  = u.x + u.y;
    float s2 = u.x*u.x + u.y*u.y;
    #pragma unroll
    for (int off = 32; off >= 1; off >>= 1){
      s  += __shfl_xor(s,  off, 64);
      s2 += __shfl_xor(s2, off, 64);
    }
    __shared__ float red[8];
    int lane = t & 63, wv = t >> 6;
    if (lane == 0){ red[wv] = s; red[4+wv] = s2; }
    __syncthreads();
    float sum  = red[0]+red[1]+red[2]+red[3];
    float sum2 = red[4]+red[5]+red[6]+red[7];
    float mean = sum * (1.0f/D_);
    float var  = sum2 * (1.0f/D_) - mean*mean;
    float inv  = rsqrtf(fmaxf(var, 0.f) + 1e-5f);
    float2 wv2 = *(const float2*)&ln1_w[2*t];
    float2 bv2 = *(const float2*)&ln1_b[2*t];
    *(unsigned*)(h + base + swz(2*t, row)) =
        pk2((u.x-mean)*inv*wv2.x + bv2.x, (u.y-mean)*inv*wv2.y + bv2.y);
    return;
  }
  if (id >= 3136){            // ---- coord projection: tv = coords·Wc * log2(e) ----
    int idx = (id - 3136)*256 + t;
    int n = idx & (N_-1);
    int hh = (idx >> 11) & (H_-1);
    int b = idx >> 14;
    float s = 0.f;
    #pragma unroll
    for (int cc = 0; cc < C_; ++cc)
      s += coords[((size_t)(b*N_+n))*C_ + cc] * Wc[cc*H_ + hh];
    tv[idx] = s * 1.44269504f;       // pre-scaled into exp2 domain
    return;
  }
  // ---- weight transpose-convert ----
  __shared__ float tile[32][33];
  const float* in; short* out; int K, NN, Kp, nx;
  if (id < 768)      { in=Wqkv; out=Wtqkv; K=512;  NN=1536; Kp=512;  nx=48; }
  else if (id < 1024){ in=Wo;   out=Wto;   K=512;  NN=512;  Kp=512;  nx=16; id-=768; }
  else if (id < 1728){ in=W1;   out=Wt1;   K=512;  NN=HID_; Kp=512;  nx=44; id-=1024; }
  else if (id < 2432){ in=W2;   out=Wt2;   K=512;  NN=HID_; Kp=512;  nx=44; id-=1728; }
  else               { in=W3;   out=Wt3;   K=HID_; NN=512;  Kp=HIDP; nx=16; id-=2432; }
  int nt0 = (id % nx)*32, kt0 = (id / nx)*32;
  int r = t >> 5, cc = t & 31;
  #pragma unroll
  for (int i=0;i<4;++i){
    int k = kt0 + i*8 + r, n = nt0 + cc;
    tile[i*8+r][cc] = (k<K && n<NN) ? in[(size_t)k*NN + n] : 0.f;
  }
  __syncthreads();
  #pragma unroll
  for (int i=0;i<4;++i){
    int n = nt0 + i*8 + r, k = kt0 + cc;
    out[(size_t)n*Kp + swz(k, n)] = sh(tile[cc][i*8+r]);
  }
}

// ---------------- LayerNorm (f32 in, swizzled bf16 out); float2 loads, u32 store ----------------
__global__ __launch_bounds__(256) void ln_kernel(const float* __restrict__ x,
        const float* __restrict__ w, const float* __restrict__ b,
        short* __restrict__ out){
  int row = blockIdx.x;
  size_t base = (size_t)row * D_;
  int t = threadIdx.x;
  float2 u = *(const float2*)&x[base + 2*t];
  float s  = u.x + u.y;
  float s2 = u.x*u.x + u.y*u.y;
  #pragma unroll
  for (int off = 32; off >= 1; off >>= 1){
    s  += __shfl_xor(s,  off, 64);
    s2 += __shfl_xor(s2, off, 64);
  }
  __shared__ float red[8];
  int lane = t & 63, wv = t >> 6;
  if (lane == 0){ red[wv] = s; red[4+wv] = s2; }
  __syncthreads();
  float sum  = red[0]+red[1]+red[2]+red[3];
  float sum2 = red[4]+red[5]+red[6]+red[7];
  float mean = sum * (1.0f/D_);
  float var  = sum2 * (1.0f/D_) - mean*mean;
  float inv  = rsqrtf(fmaxf(var, 0.f) + 1e-5f);
  float2 wv2 = *(const float2*)&w[2*t];
  float2 bv2 = *(const float2*)&b[2*t];
  *(unsigned*)(out + base + swz(2*t, row)) =
      pk2((u.x-mean)*inv*wv2.x + bv2.x, (u.y-mean)*inv*wv2.y + bv2.y);
}

// ---------------- QKV GEMM 128x128, dbuf, XCD-swizzled; q/k swapped packed epilogue ----------------
__global__ __launch_bounds__(256) void qkv_gemm(
    const short* __restrict__ A, const short* __restrict__ Bt,
    const float* __restrict__ bias,
    short* __restrict__ qb, short* __restrict__ kb, short* __restrict__ vbt){
  __shared__ short As[2][128*64];
  __shared__ short Bs[2][128*64];
  int t = threadIdx.x;
  int lane = t & 63, w = t >> 6;
  int wr = (w >> 1) * 64, wc = (w & 1) * 64;
  int wg = xcdswz(blockIdx.x, 768);
  int colblk = wg % 12, rowblk = wg / 12;     // per-XCD: 8 row-panels x all cols
  int col0 = colblk * 128, row0 = rowblk * 128;
  bool vblk = (colblk >= 8);                  // v cols 1024..1535
  floatx4 acc[4][4];
  #pragma unroll
  for (int mt=0;mt<4;++mt)
    #pragma unroll
    for (int nt=0;nt<4;++nt) acc[mt][nt] = (floatx4){0.f,0.f,0.f,0.f};
  stageG<128,64>(As[0], A  + (size_t)row0*D_, D_, t);
  stageG<128,64>(Bs[0], Bt + (size_t)col0*D_, D_, t);
  for (int ti = 0; ti < 8; ++ti){
    int cur = ti & 1;
    __syncthreads();
    if (ti + 1 < 8){
      stageG<128,64>(As[cur^1], A  + (size_t)row0*D_ + (ti+1)*64, D_, t);
      stageG<128,64>(Bs[cur^1], Bt + (size_t)col0*D_ + (ti+1)*64, D_, t);
    }
    #pragma unroll
    for (int kk = 0; kk < 64; kk += 32){
      short8 af[4], bf[4];
      #pragma unroll
      for (int mt=0;mt<4;++mt) af[mt] = fragS(As[cur], 64, wr+mt*16, lane, kk);
      #pragma unroll
      for (int nt=0;nt<4;++nt) bf[nt] = fragS(Bs[cur], 64, wc+nt*16, lane, kk);
      if (vblk){
        #pragma unroll
        for (int mt=0;mt<4;++mt)
          #pragma unroll
          for (int nt=0;nt<4;++nt)
            acc[mt][nt] = MFMA16(af[mt], bf[nt], acc[mt][nt]);   // regs=rows, lanes=cols
      } else {
        #pragma unroll
        for (int mt=0;mt<4;++mt)
          #pragma unroll
          for (int nt=0;nt<4;++nt)
            acc[mt][nt] = MFMA16(bf[nt], af[mt], acc[mt][nt]);   // regs=cols, lanes=rows
      }
    }
  }
  int quad = lane >> 4, c = lane & 15;
  if (vblk){
    // normal orientation: lane = col (d), regs = 4 consecutive rows (n) -> pack along n
    #pragma unroll
    for (int mt=0;mt<4;++mt){
      int rb0 = row0 + wr + mt*16 + quad*4;     // 4 consecutive rows, 4-aligned
      int bidx = rb0 >> 11, n0 = rb0 & (N_-1);
      #pragma unroll
      for (int nt=0;nt<4;++nt){
        int col = col0 + wc + nt*16 + c;
        int d = col & (D_-1), hh = d >> 6, hd = d & 63;
        float bc = bias[col];
        uint2v pv;
        pv.x = pk2(acc[mt][nt][0]+bc, acc[mt][nt][1]+bc);
        pv.y = pk2(acc[mt][nt][2]+bc, acc[mt][nt][3]+bc);
        *(uint2v*)(vbt + (((size_t)(bidx*H_ + hh))*DH_ + hd)*N_ + swz(n0, hd)) = pv;
      }
    }
  } else {
    // swapped orientation: lane = row (n), regs = 4 consecutive cols (d) -> pack along d
    #pragma unroll
    for (int mt=0;mt<4;++mt){
      int row = row0 + wr + mt*16 + c;
      int bidx = row >> 11, n = row & (N_-1);
      #pragma unroll
      for (int nt=0;nt<4;++nt){
        int d0 = col0 + wc + nt*16 + quad*4;    // 4 consecutive cols, 4-aligned
        floatx4 b4 = *(const floatx4*)&bias[d0];
        int which = d0 >> 9, dd = d0 & (D_-1), hh = dd >> 6, hd0 = dd & 63;
        short* dst = which ? kb : qb;
        uint2v pv;
        pv.x = pk2(acc[mt][nt][0]+b4[0], acc[mt][nt][1]+b4[1]);
        pv.y = pk2(acc[mt][nt][2]+b4[2], acc[mt][nt][3]+b4[3]);
        *(uint2v*)(dst + (((size_t)(bidx*H_ + hh))*N_ + n)*DH_ + swz(hd0, n)) = pv;
      }
    }
  }
}

// ---------------- MFMA GEMM 128x64, dbuf, XCD-swizzled, swapped, float4 epilogue ----------------
__global__ __launch_bounds__(256) void gemm64(
    const short* __restrict__ A, int lda,
    const short* __restrict__ Bt, int Ktot,
    const float* __restrict__ bias,
    const float* __restrict__ resid, float* __restrict__ outF){
  __shared__ short As[2][128*64];
  __shared__ short Bs[2][64*64];
  int t = threadIdx.x, lane = t & 63, w = t >> 6;
  int wr = w * 32;
  int wg = xcdswz(blockIdx.x, 512);
  int col0 = (wg & 7) * 64, row0 = (wg >> 3) * 128;   // per-XCD: 8 row-panels x all cols
  floatx4 acc[2][4];
  #pragma unroll
  for (int mt=0;mt<2;++mt)
    #pragma unroll
    for (int nt=0;nt<4;++nt) acc[mt][nt] = (floatx4){0.f,0.f,0.f,0.f};
  stageG<128,64>(As[0], A  + (size_t)row0*lda, lda, t);
  stageG<64,64> (Bs[0], Bt + (size_t)col0*Ktot, Ktot, t);
  const int NT = Ktot >> 6;
  for (int ti = 0; ti < NT; ++ti){
    int cur = ti & 1;
    __syncthreads();
    if (ti + 1 < NT){
      stageG<128,64>(As[cur^1], A  + (size_t)row0*lda + (ti+1)*64, lda, t);
      stageG<64,64> (Bs[cur^1], Bt + (size_t)col0*Ktot + (ti+1)*64, Ktot, t);
    }
    #pragma unroll
    for (int kk = 0; kk < 64; kk += 32){
      short8 af[2], bf[4];
      #pragma unroll
      for (int mt=0;mt<2;++mt) af[mt] = fragS(As[cur], 64, wr+mt*16, lane, kk);
      #pragma unroll
      for (int nt=0;nt<4;++nt) bf[nt] = fragS(Bs[cur], 64, nt*16, lane, kk);
      #pragma unroll
      for (int mt=0;mt<2;++mt)
        #pragma unroll
        for (int nt=0;nt<4;++nt)
          acc[mt][nt] = MFMA16(bf[nt], af[mt], acc[mt][nt]);   // swapped: regs=cols
    }
  }
  int quad = lane >> 4, c = lane & 15;
  #pragma unroll
  for (int mt=0;mt<2;++mt){
    int row = row0 + wr + mt*16 + c;
    #pragma unroll
    for (int nt=0;nt<4;++nt){
      int c0 = col0 + nt*16 + quad*4;           // 4 consecutive cols
      size_t idx = (size_t)row*D_ + c0;
      float4 rv = *(const float4*)&resid[idx];
      floatx4 b4 = *(const floatx4*)&bias[c0];
      float4 ov;
      ov.x = acc[mt][nt][0] + b4[0] + rv.x;
      ov.y = acc[mt][nt][1] + b4[1] + rv.y;
      ov.z = acc[mt][nt][2] + b4[2] + rv.z;
      ov.w = acc[mt][nt][3] + b4[3] + rv.w;
      *(float4*)&outF[idx] = ov;
    }
  }
}

// ---------------- fused SwiGLU gate GEMM: 128x64, dual-B, XCD-swizzled, packed stores ----------------
__global__ __launch_bounds__(256) void gate_gemm(
    const short* __restrict__ A,
    const short* __restrict__ Bt1, const short* __restrict__ Bt2,
    const float* __restrict__ b1, const float* __restrict__ b2,
    short* __restrict__ ff){
  __shared__ short As[128*64];
  __shared__ short B1s[64*64];
  __shared__ short B2s[64*64];
  int t = threadIdx.x, lane = t & 63, w = t >> 6;
  int wr = (w >> 1) * 64, wc = (w & 1) * 32;
  int wg = xcdswz(blockIdx.x, 1408);
  int col0 = (wg % 22) * 64, row0 = (wg / 22) * 128;  // per-XCD: 8 row-panels x all cols
  floatx4 a1[4][2], a2[4][2];
  #pragma unroll
  for (int mt=0;mt<4;++mt)
    #pragma unroll
    for (int nt=0;nt<2;++nt){
      a1[mt][nt] = (floatx4){0.f,0.f,0.f,0.f};
      a2[mt][nt] = (floatx4){0.f,0.f,0.f,0.f};
    }
  for (int k0 = 0; k0 < D_; k0 += 64){
    __syncthreads();
    stageG<128,64>(As, A + (size_t)row0*D_ + k0, D_, t);
    stageG<64,64>(B1s, Bt1 + (size_t)col0*D_ + k0, D_, t);
    stageG<64,64>(B2s, Bt2 + (size_t)col0*D_ + k0, D_, t);
    __syncthreads();
    #pragma unroll
    for (int kk = 0; kk < 64; kk += 32){
      short8 af[4], f1[2], f2[2];
      #pragma unroll
      for (int mt=0;mt<4;++mt) af[mt] = fragS(As, 64, wr+mt*16, lane, kk);
      #pragma unroll
      for (int nt=0;nt<2;++nt){
        f1[nt] = fragS(B1s, 64, wc+nt*16, lane, kk);
        f2[nt] = fragS(B2s, 64, wc+nt*16, lane, kk);
      }
      #pragma unroll
      for (int mt=0;mt<4;++mt)
        #pragma unroll
        for (int nt=0;nt<2;++nt){
          a1[mt][nt] = MFMA16(f1[nt], af[mt], a1[mt][nt]);   // swapped: regs=cols
          a2[mt][nt] = MFMA16(f2[nt], af[mt], a2[mt][nt]);
        }
    }
  }
  int quad = lane >> 4, c = lane & 15;
  #pragma unroll
  for (int mt=0;mt<4;++mt){
    int row = row0 + wr + mt*16 + c;
    size_t rbase = (size_t)row * HIDP;
    #pragma unroll
    for (int nt=0;nt<2;++nt){
      int c0 = col0 + wc + nt*16 + quad*4;      // 4 consecutive cols
      float v[4];
      #pragma unroll
      for (int r=0;r<4;++r){
        int col = c0 + r;
        float g1 = a1[mt][nt][r] + (col < HID_ ? b1[col] : 0.f);
        float g2 = a2[mt][nt][r] + (col < HID_ ? b2[col] : 0.f);
        float sig = 1.f / (1.f + __expf(-g1));
        v[r] = g1*sig*g2;
      }
      uint2v pv;
      pv.x = pk2(v[0], v[1]);
      pv.y = pk2(v[2], v[3]);
      *(uint2v*)(ff + rbase + swz(c0, row)) = pv;
    }
  }
}

// ---------------- MFMA flash attention, swapped-QK^T, in-register softmax ----------------
// 256 threads = 4 waves, one per 32 q-rows, all 128 keys. XCD-swizzled grid groups the
// 16 q-tiles of each (b,h) on one XCD (K/V L2-resident per XCD). kb4 loop software-
// pipelined one-ahead: QK^T(kb4+1) MFMAs issued before softmax/PV(kb4) VALU phase.
#define EXP2SC 0.18033688011112042f   // 0.125 * log2(e)

#define ZERO_S(S) { \
  S[0][0] = (floatx4){0.f,0.f,0.f,0.f}; S[0][1] = (floatx4){0.f,0.f,0.f,0.f}; \
  S[1][0] = (floatx4){0.f,0.f,0.f,0.f}; S[1][1] = (floatx4){0.f,0.f,0.f,0.f}; }

#define QKT(S, kb) { \
  _Pragma("unroll") \
  for (int kh=0;kh<2;++kh){ \
    short8 kf0 = fragS(Kc, 64, (kb)*32,      lane, kh*32); \
    short8 kf1 = fragS(Kc, 64, (kb)*32 + 16, lane, kh*32); \
    _Pragma("unroll") \
    for (int mt=0;mt<2;++mt){ \
      S[0][mt] = MFMA16(kf0, qf[mt][kh], S[0][mt]); \
      S[1][mt] = MFMA16(kf1, qf[mt][kh], S[1][mt]); \
    } \
  } }

#define SOFTPV(S, kb) { \
  floatx4 t0 = *(const floatx4*)&tsc[(kb)*32 + quad*4]; \
  floatx4 t1 = *(const floatx4*)&tsc[(kb)*32 + 16 + quad*4]; \
  short8 pbf[2]; \
  _Pragma("unroll") \
  for (int mt=0;mt<2;++mt){ \
    float p0[4], p1[4]; \
    _Pragma("unroll") \
    for (int r=0;r<4;++r){ \
      p0[r] = __builtin_amdgcn_exp2f(fmaf(S[0][mt][r], EXP2SC, -t0[r])); \
      p1[r] = __builtin_amdgcn_exp2f(fmaf(S[1][mt][r], EXP2SC, -t1[r])); \
    } \
    l_i[mt] += (p0[0]+p0[1]) + (p0[2]+p0[3]) + (p1[0]+p1[1]) + (p1[2]+p1[3]); \
    unsigned X0 = pk2(p0[0], p0[1]), X1 = pk2(p0[2], p0[3]); \
    unsigned Y0 = pk2(p1[0], p1[1]), Y1 = pk2(p1[2], p1[3]); \
    auto u0 = __builtin_amdgcn_permlane32_swap(X0, Y0, false, false); \
    auto v0 = __builtin_amdgcn_permlane16_swap(u0[0], u0[1], false, false); \
    auto u1 = __builtin_amdgcn_permlane32_swap(X1, Y1, false, false); \
    auto v1 = __builtin_amdgcn_permlane16_swap(u1[0], u1[1], false, false); \
    union { short8 s; unsigned uu[4]; } pb; \
    pb.uu[0] = v0[0]; pb.uu[1] = v1[0]; pb.uu[2] = v0[1]; pb.uu[3] = v1[1]; \
    pbf[mt] = pb.s; \
  } \
  _Pragma("unroll") \
  for (int nt=0;nt<4;++nt){ \
    short8 vf = fragS(Vc, 128, nt*16, lane, (kb)*32); \
    _Pragma("unroll") \
    for (int mt=0;mt<2;++mt) \
      O[mt][nt] = MFMA16(vf, pbf[mt], O[mt][nt]); \
  } }

__global__ __launch_bounds__(256) void attn_mfma(
    const short* __restrict__ qb, const short* __restrict__ kbuf,
    const short* __restrict__ vbt, const float* __restrict__ tv,
    short* __restrict__ o){
  __shared__ short Ks2[2][128*64];        // [key][hd] swizzled
  __shared__ short Vt2[2][64*128];        // [hd][key] swizzled
  __shared__ __align__(16) float tsAll[2048];  // tv row (pre-scaled by log2e)
  int wg = xcdswz(blockIdx.x, 512);
  int bh = wg >> 4, qt = wg & 15;          // per-XCD: 4 bh x all 16 q-tiles
  int b = bh >> 3, h = bh & 7;
  int t = threadIdx.x, lane = t & 63, w = t >> 6;
  int quad = lane >> 4, c = lane & 15;
  const short* Kbase = kbuf + (size_t)bh*N_*DH_;
  const short* Vbase = vbt  + (size_t)bh*DH_*N_;

  #pragma unroll
  for (int i = 0; i < 2; ++i)
    *(floatx4*)&tsAll[t*8 + i*4] = *(const floatx4*)&tv[(size_t)bh*N_ + t*8 + i*4];
  // stage Q into buffer 1; stage kt=0 K/V into buffer 0
  stageG<128,64>(Ks2[1], qb + ((size_t)bh*N_ + qt*128)*DH_, DH_, t);
  stageG<128,64>(Ks2[0], Kbase, DH_, t);
  stageG<64,128>(Vt2[0], Vbase, N_, t);
  __syncthreads();
  short8 qf[2][2];
  #pragma unroll
  for (int mt=0;mt<2;++mt)
    #pragma unroll
    for (int kh=0;kh<2;++kh)
      qf[mt][kh] = fragS(Ks2[1], 64, w*32 + mt*16, lane, kh*32);
  floatx4 O[2][4];
  float l_i[2] = {0.f, 0.f};
  #pragma unroll
  for (int mt=0;mt<2;++mt)
    #pragma unroll
    for (int nt=0;nt<4;++nt) O[mt][nt] = (floatx4){0.f,0.f,0.f,0.f};
  __syncthreads();   // all waves finished reading Q before buffer 1 is restaged

  for (int kt = 0; kt < N_/128; ++kt){
    int cur = kt & 1;
    if (kt + 1 < N_/128){   // issue next-tile stage; overlaps this tile's compute
      stageG<128,64>(Ks2[cur^1], Kbase + (size_t)(kt+1)*128*DH_, DH_, t);
      stageG<64,128>(Vt2[cur^1], Vbase + (kt+1)*128, N_, t);
    }
    const short* Kc  = Ks2[cur];
    const short* Vc  = Vt2[cur];
    const float* tsc = tsAll + kt*128;
    // one-ahead pipelined kb4 loop (static Sa/Sb names; QK(next) before SOFTPV(cur))
    floatx4 Sa[2][2], Sb[2][2];
    ZERO_S(Sa); QKT(Sa, 0);
    ZERO_S(Sb); QKT(Sb, 1);
    SOFTPV(Sa, 0);
    ZERO_S(Sa); QKT(Sa, 2);
    SOFTPV(Sb, 1);
    ZERO_S(Sb); QKT(Sb, 3);
    SOFTPV(Sa, 2);
    SOFTPV(Sb, 3);
    __syncthreads();
  }
  // reduce l over quads (keys spread across quads+regs); lane&15 = q
  #pragma unroll
  for (int mt=0;mt<2;++mt){
    float l = l_i[mt];
    l += __shfl_xor(l, 16, 64);
    l += __shfl_xor(l, 32, 64);
    float invl = 1.f / l;
    int qrow = qt*128 + w*32 + mt*16 + c;
    size_t rb = ((size_t)b*N_ + qrow)*(size_t)D_;
    #pragma unroll
    for (int nt=0;nt<4;++nt){
      int d0 = h*DH_ + nt*16 + quad*4;     // 4 consecutive d per lane
      uint2v pv;
      pv.x = pk2(O[mt][nt][0]*invl, O[mt][nt][1]*invl);
      pv.y = pk2(O[mt][nt][2]*invl, O[mt][nt][3]*invl);
      *(uint2v*)(o + rb + swz(d0, qrow)) = pv;   // swz keeps 4-short runs intact
    }
  }
}

extern "C" void kernel_launch(void* const* d_in, const int* in_sizes, int n_in,
                              void* d_out, int out_size, void* d_ws, size_t ws_size,
                              hipStream_t stream){
  const float* x      = (const float*)d_in[0];
  const float* coords = (const float*)d_in[1];
  const float* ln1_w  = (const float*)d_in[2];
  const float* ln1_b  = (const float*)d_in[3];
  const float* ln2_w  = (const float*)d_in[4];
  const float* ln2_b  = (const float*)d_in[5];
  const float* Wqkv   = (const float*)d_in[6];
  const float* bqkv   = (const float*)d_in[7];
  const float* Wo     = (const float*)d_in[8];
  const float* bo     = (const float*)d_in[9];
  const float* Wc     = (const float*)d_in[10];
  // d_in[11] = bc: constant over softmax axis -> no effect on output
  const float* W1     = (const float*)d_in[12];
  const float* b1     = (const float*)d_in[13];
  const float* W2     = (const float*)d_in[14];
  const float* b2     = (const float*)d_in[15];
  const float* W3     = (const float*)d_in[16];
  const float* b3     = (const float*)d_in[17];

  // ws layout (peak 40.2 MB), all bf16 raw shorts; swizzled layouts as documented
  char* ws = (char*)d_ws;
  short* Wtqkv = (short*)(ws);                         // [1536][512]
  short* Wto   = (short*)(ws + 1572864);               // [512][512]
  short* Wt1   = (short*)(ws + 2097152);               // [1408][512]
  short* Wt2   = (short*)(ws + 3538944);               // [1408][512]
  short* Wt3   = (short*)(ws + 4980736);               // [512][1408]
  float* tv    = (float*)(ws + 6422528);               // [32][2048]
  short* h     = (short*)(ws + 6684672);               // [8192][512]
  short* qb    = (short*)(ws + 15073280);              // 8 MB
  short* kb    = (short*)(ws + 23461888);              // 8 MB
  short* vbt   = (short*)(ws + 31850496);              // 8 MB  [bh][hd][n]
  short* o     = h;                                    // alias: h dead after qkv
  short* h2    = h;                                    // alias: o dead after wo
  short* ff    = qb;                                   // alias: q/k/v dead after attn
  float* x1    = (float*)d_out;                        // f32 [8192][512] = d_out

  // blocks: [0,3136) weights, [3136,3392) coord proj, [3392,11584) LN1
  convT_all<<<dim3(11584), dim3(256), 0, stream>>>(Wqkv, Wo, W1, W2, W3,
      Wtqkv, Wto, Wt1, Wt2, Wt3, coords, Wc, tv, x, ln1_w, ln1_b, h);
  qkv_gemm<<<dim3(768), dim3(256), 0, stream>>>(h, Wtqkv, bqkv, qb, kb, vbt);
  attn_mfma<<<dim3(512), dim3(256), 0, stream>>>(qb, kb, vbt, tv, o);
  gemm64<<<dim3(512), dim3(256), 0, stream>>>(o, 512, Wto, 512, bo, x, x1);
  ln_kernel<<<dim3(ROWS_), dim3(256), 0, stream>>>(x1, ln2_w, ln2_b, h2);
  gate_gemm<<<dim3(1408), dim3(256), 0, stream>>>(h2, Wt1, Wt2, b1, b2, ff);
  gemm64<<<dim3(512), dim3(256), 0, stream>>>(ff, HIDP, Wt3, HIDP, b3, x1, x1);
}

// Round 7
// 273.640 us; speedup vs baseline: 1.3160x; 1.0129x over previous
//
#include <hip/hip_runtime.h>
#include <hip/hip_bf16.h>
#include <math.h>

#define B_   4
#define N_   2048
#define D_   512
#define H_   8
#define DH_  64
#define C_   3
#define HID_ 1365
#define HIDP 1408          // padded HID (11 * 128)
#define ROWS_ (B_*N_)      // 8192
#define TD_  (3*D_)        // 1536

typedef __attribute__((ext_vector_type(8))) short short8;   // 8 bf16 = 4 VGPR
typedef __attribute__((ext_vector_type(4))) float floatx4;
typedef __attribute__((ext_vector_type(2))) unsigned uint2v;

#define MFMA16(a,b,c) __builtin_amdgcn_mfma_f32_16x16x32_bf16(a,b,c,0,0,0)

typedef __attribute__((address_space(3))) unsigned lds_u32;
typedef __attribute__((address_space(1))) unsigned glb_u32;

__device__ __forceinline__ short sh(float v){
  union { __hip_bfloat16 b; short s; } u;
  u.b = __float2bfloat16(v);
  return u.s;
}

// pack two floats into one u32 of 2 bf16 (low = a); compiler fuses to cvt_pk
__device__ __forceinline__ unsigned pk2(float a, float b){
  union { short s[2]; unsigned u; } z;
  z.s[0] = sh(a); z.s[1] = sh(b);
  return z.u;
}

// global-layout segment swizzle: within each 64-short k-block, 16B segment s -> s ^ (row&7)
__device__ __forceinline__ int swz(int col, int row){
  return (col & ~63) | (col & 7) | ((((col >> 3) & 7) ^ (row & 7)) << 3);
}

// XCD-aware bijective block remap (nwg % 8 == 0): consecutive remapped ids stay on one XCD
__device__ __forceinline__ int xcdswz(int bid, int nwg){
  return (bid & 7) * (nwg >> 3) + (bid >> 3);
}

// async global->LDS stage: ROWS rows of PITCH shorts (16B-swizzled global layout assumed).
template<int ROWS, int PITCH, int WAVES = 4>
__device__ __forceinline__ void stageG(short* __restrict__ lds,
    const short* __restrict__ g, int ldg, int t){
  const int LPR = PITCH/8;          // lanes per row
  const int RPI = 64/LPR;           // rows per instruction
  const int PW  = (ROWS/RPI)/WAVES; // instructions per wave
  int lane = t & 63, w = t >> 6;
  #pragma unroll
  for (int i = 0; i < PW; ++i){
    int r0  = (w*PW + i)*RPI;
    int row = r0 + lane/LPR;
    const short* ga = g + (size_t)row*ldg + (lane % LPR)*8;
    short* la = lds + r0*PITCH;     // wave-uniform; HW adds lane*16B
    __builtin_amdgcn_global_load_lds((const glb_u32*)ga, (lds_u32*)la, 16, 0, 0);
  }
}

// MFMA fragment from unpadded swizzled LDS tile
__device__ __forceinline__ short8 fragS(const short* __restrict__ lds, int pitch,
    int mbase, int lane, int kk){
  int row  = mbase + (lane & 15);
  int seg  = (kk >> 3) + (lane >> 4);
  int phys = seg ^ (row & 7);
  return *(const short8*)(lds + row*pitch + phys*8);
}

// ---------------- merged: weight transpose-convert (swizzled) + coord proj + LN1 ----------------
__global__ __launch_bounds__(256) void convT_all(
    const float* __restrict__ Wqkv, const float* __restrict__ Wo,
    const float* __restrict__ W1, const float* __restrict__ W2,
    const float* __restrict__ W3,
    short* __restrict__ Wtqkv, short* __restrict__ Wto,
    short* __restrict__ Wt1, short* __restrict__ Wt2, short* __restrict__ Wt3,
    const float* __restrict__ coords, const float* __restrict__ Wc,
    float* __restrict__ tv,
    const float* __restrict__ x, const float* __restrict__ ln1_w,
    const float* __restrict__ ln1_b, short* __restrict__ h){
  int id = blockIdx.x;
  int t = threadIdx.x;
  if (id >= 3392){            // ---- LN1 rows (float2 loads, packed u32 store) ----
    int row = id - 3392;
    size_t base = (size_t)row * D_;
    float2 u = *(const float2*)&x[base + 2*t];
    float s  = u.x + u.y;
    float s2 = u.x*u.x + u.y*u.y;
    #pragma unroll
    for (int off = 32; off >= 1; off >>= 1){
      s  += __shfl_xor(s,  off, 64);
      s2 += __shfl_xor(s2, off, 64);
    }
    __shared__ float red[8];
    int lane = t & 63, wv = t >> 6;
    if (lane == 0){ red[wv] = s; red[4+wv] = s2; }
    __syncthreads();
    float sum  = red[0]+red[1]+red[2]+red[3];
    float sum2 = red[4]+red[5]+red[6]+red[7];
    float mean = sum * (1.0f/D_);
    float var  = sum2 * (1.0f/D_) - mean*mean;
    float inv  = rsqrtf(fmaxf(var, 0.f) + 1e-5f);
    float2 wv2 = *(const float2*)&ln1_w[2*t];
    float2 bv2 = *(const float2*)&ln1_b[2*t];
    *(unsigned*)(h + base + swz(2*t, row)) =
        pk2((u.x-mean)*inv*wv2.x + bv2.x, (u.y-mean)*inv*wv2.y + bv2.y);
    return;
  }
  if (id >= 3136){            // ---- coord projection: tv = coords·Wc * log2(e) ----
    int idx = (id - 3136)*256 + t;
    int n = idx & (N_-1);
    int hh = (idx >> 11) & (H_-1);
    int b = idx >> 14;
    float s = 0.f;
    #pragma unroll
    for (int cc = 0; cc < C_; ++cc)
      s += coords[((size_t)(b*N_+n))*C_ + cc] * Wc[cc*H_ + hh];
    tv[idx] = s * 1.44269504f;       // pre-scaled into exp2 domain
    return;
  }
  // ---- weight transpose-convert ----
  __shared__ float tile[32][33];
  const float* in; short* out; int K, NN, Kp, nx;
  if (id < 768)      { in=Wqkv; out=Wtqkv; K=512;  NN=1536; Kp=512;  nx=48; }
  else if (id < 1024){ in=Wo;   out=Wto;   K=512;  NN=512;  Kp=512;  nx=16; id-=768; }
  else if (id < 1728){ in=W1;   out=Wt1;   K=512;  NN=HID_; Kp=512;  nx=44; id-=1024; }
  else if (id < 2432){ in=W2;   out=Wt2;   K=512;  NN=HID_; Kp=512;  nx=44; id-=1728; }
  else               { in=W3;   out=Wt3;   K=HID_; NN=512;  Kp=HIDP; nx=16; id-=2432; }
  int nt0 = (id % nx)*32, kt0 = (id / nx)*32;
  int r = t >> 5, cc = t & 31;
  #pragma unroll
  for (int i=0;i<4;++i){
    int k = kt0 + i*8 + r, n = nt0 + cc;
    tile[i*8+r][cc] = (k<K && n<NN) ? in[(size_t)k*NN + n] : 0.f;
  }
  __syncthreads();
  #pragma unroll
  for (int i=0;i<4;++i){
    int n = nt0 + i*8 + r, k = kt0 + cc;
    out[(size_t)n*Kp + swz(k, n)] = sh(tile[cc][i*8+r]);
  }
}

// ---------------- LayerNorm (f32 in, swizzled bf16 out); float2 loads, u32 store ----------------
__global__ __launch_bounds__(256) void ln_kernel(const float* __restrict__ x,
        const float* __restrict__ w, const float* __restrict__ b,
        short* __restrict__ out){
  int row = blockIdx.x;
  size_t base = (size_t)row * D_;
  int t = threadIdx.x;
  float2 u = *(const float2*)&x[base + 2*t];
  float s  = u.x + u.y;
  float s2 = u.x*u.x + u.y*u.y;
  #pragma unroll
  for (int off = 32; off >= 1; off >>= 1){
    s  += __shfl_xor(s,  off, 64);
    s2 += __shfl_xor(s2, off, 64);
  }
  __shared__ float red[8];
  int lane = t & 63, wv = t >> 6;
  if (lane == 0){ red[wv] = s; red[4+wv] = s2; }
  __syncthreads();
  float sum  = red[0]+red[1]+red[2]+red[3];
  float sum2 = red[4]+red[5]+red[6]+red[7];
  float mean = sum * (1.0f/D_);
  float var  = sum2 * (1.0f/D_) - mean*mean;
  float inv  = rsqrtf(fmaxf(var, 0.f) + 1e-5f);
  float2 wv2 = *(const float2*)&w[2*t];
  float2 bv2 = *(const float2*)&b[2*t];
  *(unsigned*)(out + base + swz(2*t, row)) =
      pk2((u.x-mean)*inv*wv2.x + bv2.x, (u.y-mean)*inv*wv2.y + bv2.y);
}

// ---------------- QKV GEMM 128x128, dbuf, XCD-swizzled; q/k swapped packed epilogue ----------------
__global__ __launch_bounds__(256) void qkv_gemm(
    const short* __restrict__ A, const short* __restrict__ Bt,
    const float* __restrict__ bias,
    short* __restrict__ qb, short* __restrict__ kb, short* __restrict__ vbt){
  __shared__ short As[2][128*64];
  __shared__ short Bs[2][128*64];
  int t = threadIdx.x;
  int lane = t & 63, w = t >> 6;
  int wr = (w >> 1) * 64, wc = (w & 1) * 64;
  int wg = xcdswz(blockIdx.x, 768);
  int colblk = wg % 12, rowblk = wg / 12;     // per-XCD: 8 row-panels x all cols
  int col0 = colblk * 128, row0 = rowblk * 128;
  bool vblk = (colblk >= 8);                  // v cols 1024..1535
  floatx4 acc[4][4];
  #pragma unroll
  for (int mt=0;mt<4;++mt)
    #pragma unroll
    for (int nt=0;nt<4;++nt) acc[mt][nt] = (floatx4){0.f,0.f,0.f,0.f};
  stageG<128,64>(As[0], A  + (size_t)row0*D_, D_, t);
  stageG<128,64>(Bs[0], Bt + (size_t)col0*D_, D_, t);
  for (int ti = 0; ti < 8; ++ti){
    int cur = ti & 1;
    __syncthreads();
    if (ti + 1 < 8){
      stageG<128,64>(As[cur^1], A  + (size_t)row0*D_ + (ti+1)*64, D_, t);
      stageG<128,64>(Bs[cur^1], Bt + (size_t)col0*D_ + (ti+1)*64, D_, t);
    }
    #pragma unroll
    for (int kk = 0; kk < 64; kk += 32){
      short8 af[4], bf[4];
      #pragma unroll
      for (int mt=0;mt<4;++mt) af[mt] = fragS(As[cur], 64, wr+mt*16, lane, kk);
      #pragma unroll
      for (int nt=0;nt<4;++nt) bf[nt] = fragS(Bs[cur], 64, wc+nt*16, lane, kk);
      if (vblk){
        #pragma unroll
        for (int mt=0;mt<4;++mt)
          #pragma unroll
          for (int nt=0;nt<4;++nt)
            acc[mt][nt] = MFMA16(af[mt], bf[nt], acc[mt][nt]);   // regs=rows, lanes=cols
      } else {
        #pragma unroll
        for (int mt=0;mt<4;++mt)
          #pragma unroll
          for (int nt=0;nt<4;++nt)
            acc[mt][nt] = MFMA16(bf[nt], af[mt], acc[mt][nt]);   // regs=cols, lanes=rows
      }
    }
  }
  int quad = lane >> 4, c = lane & 15;
  if (vblk){
    // normal orientation: lane = col (d), regs = 4 consecutive rows (n) -> pack along n
    #pragma unroll
    for (int mt=0;mt<4;++mt){
      int rb0 = row0 + wr + mt*16 + quad*4;     // 4 consecutive rows, 4-aligned
      int bidx = rb0 >> 11, n0 = rb0 & (N_-1);
      #pragma unroll
      for (int nt=0;nt<4;++nt){
        int col = col0 + wc + nt*16 + c;
        int d = col & (D_-1), hh = d >> 6, hd = d & 63;
        float bc = bias[col];
        uint2v pv;
        pv.x = pk2(acc[mt][nt][0]+bc, acc[mt][nt][1]+bc);
        pv.y = pk2(acc[mt][nt][2]+bc, acc[mt][nt][3]+bc);
        *(uint2v*)(vbt + (((size_t)(bidx*H_ + hh))*DH_ + hd)*N_ + swz(n0, hd)) = pv;
      }
    }
  } else {
    // swapped orientation: lane = row (n), regs = 4 consecutive cols (d) -> pack along d
    #pragma unroll
    for (int mt=0;mt<4;++mt){
      int row = row0 + wr + mt*16 + c;
      int bidx = row >> 11, n = row & (N_-1);
      #pragma unroll
      for (int nt=0;nt<4;++nt){
        int d0 = col0 + wc + nt*16 + quad*4;    // 4 consecutive cols, 4-aligned
        floatx4 b4 = *(const floatx4*)&bias[d0];
        int which = d0 >> 9, dd = d0 & (D_-1), hh = dd >> 6, hd0 = dd & 63;
        short* dst = which ? kb : qb;
        uint2v pv;
        pv.x = pk2(acc[mt][nt][0]+b4[0], acc[mt][nt][1]+b4[1]);
        pv.y = pk2(acc[mt][nt][2]+b4[2], acc[mt][nt][3]+b4[3]);
        *(uint2v*)(dst + (((size_t)(bidx*H_ + hh))*N_ + n)*DH_ + swz(hd0, n)) = pv;
      }
    }
  }
}

// ---------------- MFMA GEMM 128x64, dbuf, XCD-swizzled, swapped, float4 epilogue ----------------
__global__ __launch_bounds__(256) void gemm64(
    const short* __restrict__ A, int lda,
    const short* __restrict__ Bt, int Ktot,
    const float* __restrict__ bias,
    const float* __restrict__ resid, float* __restrict__ outF){
  __shared__ short As[2][128*64];
  __shared__ short Bs[2][64*64];
  int t = threadIdx.x, lane = t & 63, w = t >> 6;
  int wr = w * 32;
  int wg = xcdswz(blockIdx.x, 512);
  int col0 = (wg & 7) * 64, row0 = (wg >> 3) * 128;   // per-XCD: 8 row-panels x all cols
  floatx4 acc[2][4];
  #pragma unroll
  for (int mt=0;mt<2;++mt)
    #pragma unroll
    for (int nt=0;nt<4;++nt) acc[mt][nt] = (floatx4){0.f,0.f,0.f,0.f};
  stageG<128,64>(As[0], A  + (size_t)row0*lda, lda, t);
  stageG<64,64> (Bs[0], Bt + (size_t)col0*Ktot, Ktot, t);
  const int NT = Ktot >> 6;
  for (int ti = 0; ti < NT; ++ti){
    int cur = ti & 1;
    __syncthreads();
    if (ti + 1 < NT){
      stageG<128,64>(As[cur^1], A  + (size_t)row0*lda + (ti+1)*64, lda, t);
      stageG<64,64> (Bs[cur^1], Bt + (size_t)col0*Ktot + (ti+1)*64, Ktot, t);
    }
    #pragma unroll
    for (int kk = 0; kk < 64; kk += 32){
      short8 af[2], bf[4];
      #pragma unroll
      for (int mt=0;mt<2;++mt) af[mt] = fragS(As[cur], 64, wr+mt*16, lane, kk);
      #pragma unroll
      for (int nt=0;nt<4;++nt) bf[nt] = fragS(Bs[cur], 64, nt*16, lane, kk);
      #pragma unroll
      for (int mt=0;mt<2;++mt)
        #pragma unroll
        for (int nt=0;nt<4;++nt)
          acc[mt][nt] = MFMA16(bf[nt], af[mt], acc[mt][nt]);   // swapped: regs=cols
    }
  }
  int quad = lane >> 4, c = lane & 15;
  #pragma unroll
  for (int mt=0;mt<2;++mt){
    int row = row0 + wr + mt*16 + c;
    #pragma unroll
    for (int nt=0;nt<4;++nt){
      int c0 = col0 + nt*16 + quad*4;           // 4 consecutive cols
      size_t idx = (size_t)row*D_ + c0;
      float4 rv = *(const float4*)&resid[idx];
      floatx4 b4 = *(const floatx4*)&bias[c0];
      float4 ov;
      ov.x = acc[mt][nt][0] + b4[0] + rv.x;
      ov.y = acc[mt][nt][1] + b4[1] + rv.y;
      ov.z = acc[mt][nt][2] + b4[2] + rv.z;
      ov.w = acc[mt][nt][3] + b4[3] + rv.w;
      *(float4*)&outF[idx] = ov;
    }
  }
}

// ---------------- fused SwiGLU gate GEMM: 128x64, dual-B, XCD-swizzled, packed stores ----------------
__global__ __launch_bounds__(256) void gate_gemm(
    const short* __restrict__ A,
    const short* __restrict__ Bt1, const short* __restrict__ Bt2,
    const float* __restrict__ b1, const float* __restrict__ b2,
    short* __restrict__ ff){
  __shared__ short As[128*64];
  __shared__ short B1s[64*64];
  __shared__ short B2s[64*64];
  int t = threadIdx.x, lane = t & 63, w = t >> 6;
  int wr = (w >> 1) * 64, wc = (w & 1) * 32;
  int wg = xcdswz(blockIdx.x, 1408);
  int col0 = (wg % 22) * 64, row0 = (wg / 22) * 128;  // per-XCD: 8 row-panels x all cols
  floatx4 a1[4][2], a2[4][2];
  #pragma unroll
  for (int mt=0;mt<4;++mt)
    #pragma unroll
    for (int nt=0;nt<2;++nt){
      a1[mt][nt] = (floatx4){0.f,0.f,0.f,0.f};
      a2[mt][nt] = (floatx4){0.f,0.f,0.f,0.f};
    }
  for (int k0 = 0; k0 < D_; k0 += 64){
    __syncthreads();
    stageG<128,64>(As, A + (size_t)row0*D_ + k0, D_, t);
    stageG<64,64>(B1s, Bt1 + (size_t)col0*D_ + k0, D_, t);
    stageG<64,64>(B2s, Bt2 + (size_t)col0*D_ + k0, D_, t);
    __syncthreads();
    #pragma unroll
    for (int kk = 0; kk < 64; kk += 32){
      short8 af[4], f1[2], f2[2];
      #pragma unroll
      for (int mt=0;mt<4;++mt) af[mt] = fragS(As, 64, wr+mt*16, lane, kk);
      #pragma unroll
      for (int nt=0;nt<2;++nt){
        f1[nt] = fragS(B1s, 64, wc+nt*16, lane, kk);
        f2[nt] = fragS(B2s, 64, wc+nt*16, lane, kk);
      }
      #pragma unroll
      for (int mt=0;mt<4;++mt)
        #pragma unroll
        for (int nt=0;nt<2;++nt){
          a1[mt][nt] = MFMA16(f1[nt], af[mt], a1[mt][nt]);   // swapped: regs=cols
          a2[mt][nt] = MFMA16(f2[nt], af[mt], a2[mt][nt]);
        }
    }
  }
  int quad = lane >> 4, c = lane & 15;
  #pragma unroll
  for (int mt=0;mt<4;++mt){
    int row = row0 + wr + mt*16 + c;
    size_t rbase = (size_t)row * HIDP;
    #pragma unroll
    for (int nt=0;nt<2;++nt){
      int c0 = col0 + wc + nt*16 + quad*4;      // 4 consecutive cols
      float v[4];
      #pragma unroll
      for (int r=0;r<4;++r){
        int col = c0 + r;
        float g1 = a1[mt][nt][r] + (col < HID_ ? b1[col] : 0.f);
        float g2 = a2[mt][nt][r] + (col < HID_ ? b2[col] : 0.f);
        float sig = 1.f / (1.f + __expf(-g1));
        v[r] = g1*sig*g2;
      }
      uint2v pv;
      pv.x = pk2(v[0], v[1]);
      pv.y = pk2(v[2], v[3]);
      *(uint2v*)(ff + rbase + swz(c0, row)) = pv;
    }
  }
}

// ---------------- MFMA flash attention, swapped-QK^T, in-register softmax ----------------
// 256 threads = 4 waves, one per 32 q-rows, all 128 keys. XCD-swizzled grid (K/V
// L2-resident per XCD). l-sum computed via ones-MFMA (offloads VALU->MFMA pipe, no
// final shuffle). t-vectors hoisted per kt. setprio(1) around MFMA clusters (T5).
#define EXP2SC 0.18033688011112042f   // 0.125 * log2(e)

#define ZERO_S(S) { \
  S[0][0] = (floatx4){0.f,0.f,0.f,0.f}; S[0][1] = (floatx4){0.f,0.f,0.f,0.f}; \
  S[1][0] = (floatx4){0.f,0.f,0.f,0.f}; S[1][1] = (floatx4){0.f,0.f,0.f,0.f}; }

#define QKT(S, kb) { \
  _Pragma("unroll") \
  for (int kh=0;kh<2;++kh){ \
    short8 kf0 = fragS(Kc, 64, (kb)*32,      lane, kh*32); \
    short8 kf1 = fragS(Kc, 64, (kb)*32 + 16, lane, kh*32); \
    __builtin_amdgcn_s_setprio(1); \
    _Pragma("unroll") \
    for (int mt=0;mt<2;++mt){ \
      S[0][mt] = MFMA16(kf0, qf[mt][kh], S[0][mt]); \
      S[1][mt] = MFMA16(kf1, qf[mt][kh], S[1][mt]); \
    } \
    __builtin_amdgcn_s_setprio(0); \
  } }

#define SOFTPV(S, kb) { \
  short8 pbf[2]; \
  _Pragma("unroll") \
  for (int mt=0;mt<2;++mt){ \
    float p0[4], p1[4]; \
    _Pragma("unroll") \
    for (int r=0;r<4;++r){ \
      p0[r] = __builtin_amdgcn_exp2f(fmaf(S[0][mt][r], EXP2SC, -treg[(kb)*2][r])); \
      p1[r] = __builtin_amdgcn_exp2f(fmaf(S[1][mt][r], EXP2SC, -treg[(kb)*2+1][r])); \
    } \
    unsigned X0 = pk2(p0[0], p0[1]), X1 = pk2(p0[2], p0[3]); \
    unsigned Y0 = pk2(p1[0], p1[1]), Y1 = pk2(p1[2], p1[3]); \
    auto u0 = __builtin_amdgcn_permlane32_swap(X0, Y0, false, false); \
    auto v0 = __builtin_amdgcn_permlane16_swap(u0[0], u0[1], false, false); \
    auto u1 = __builtin_amdgcn_permlane32_swap(X1, Y1, false, false); \
    auto v1 = __builtin_amdgcn_permlane16_swap(u1[0], u1[1], false, false); \
    union { short8 s; unsigned uu[4]; } pb; \
    pb.uu[0] = v0[0]; pb.uu[1] = v1[0]; pb.uu[2] = v0[1]; pb.uu[3] = v1[1]; \
    pbf[mt] = pb.s; \
  } \
  __builtin_amdgcn_s_setprio(1); \
  _Pragma("unroll") \
  for (int nt=0;nt<4;++nt){ \
    short8 vf = fragS(Vc, 128, nt*16, lane, (kb)*32); \
    _Pragma("unroll") \
    for (int mt=0;mt<2;++mt) \
      O[mt][nt] = MFMA16(vf, pbf[mt], O[mt][nt]); \
  } \
  Lacc[0] = MFMA16(ones8, pbf[0], Lacc[0]); \
  Lacc[1] = MFMA16(ones8, pbf[1], Lacc[1]); \
  __builtin_amdgcn_s_setprio(0); \
  }

__global__ __launch_bounds__(256) void attn_mfma(
    const short* __restrict__ qb, const short* __restrict__ kbuf,
    const short* __restrict__ vbt, const float* __restrict__ tv,
    short* __restrict__ o){
  __shared__ short Ks2[2][128*64];        // [key][hd] swizzled
  __shared__ short Vt2[2][64*128];        // [hd][key] swizzled
  __shared__ __align__(16) float tsAll[2048];  // tv row (pre-scaled by log2e)
  int wg = xcdswz(blockIdx.x, 512);
  int bh = wg >> 4, qt = wg & 15;          // per-XCD: 4 bh x all 16 q-tiles
  int b = bh >> 3, h = bh & 7;
  int t = threadIdx.x, lane = t & 63, w = t >> 6;
  int quad = lane >> 4, c = lane & 15;
  const short* Kbase = kbuf + (size_t)bh*N_*DH_;
  const short* Vbase = vbt  + (size_t)bh*DH_*N_;
  const short ONEB = (short)0x3F80;        // bf16 1.0
  short8 ones8 = {ONEB,ONEB,ONEB,ONEB,ONEB,ONEB,ONEB,ONEB};

  #pragma unroll
  for (int i = 0; i < 2; ++i)
    *(floatx4*)&tsAll[t*8 + i*4] = *(const floatx4*)&tv[(size_t)bh*N_ + t*8 + i*4];
  // stage Q into buffer 1; stage kt=0 K/V into buffer 0
  stageG<128,64>(Ks2[1], qb + ((size_t)bh*N_ + qt*128)*DH_, DH_, t);
  stageG<128,64>(Ks2[0], Kbase, DH_, t);
  stageG<64,128>(Vt2[0], Vbase, N_, t);
  __syncthreads();
  short8 qf[2][2];
  #pragma unroll
  for (int mt=0;mt<2;++mt)
    #pragma unroll
    for (int kh=0;kh<2;++kh)
      qf[mt][kh] = fragS(Ks2[1], 64, w*32 + mt*16, lane, kh*32);
  floatx4 O[2][4];
  floatx4 Lacc[2];
  Lacc[0] = (floatx4){0.f,0.f,0.f,0.f};
  Lacc[1] = (floatx4){0.f,0.f,0.f,0.f};
  #pragma unroll
  for (int mt=0;mt<2;++mt)
    #pragma unroll
    for (int nt=0;nt<4;++nt) O[mt][nt] = (floatx4){0.f,0.f,0.f,0.f};
  __syncthreads();   // all waves finished reading Q before buffer 1 is restaged

  for (int kt = 0; kt < N_/128; ++kt){
    int cur = kt & 1;
    if (kt + 1 < N_/128){   // issue next-tile stage; overlaps this tile's compute
      stageG<128,64>(Ks2[cur^1], Kbase + (size_t)(kt+1)*128*DH_, DH_, t);
      stageG<64,128>(Vt2[cur^1], Vbase + (kt+1)*128, N_, t);
    }
    const short* Kc  = Ks2[cur];
    const short* Vc  = Vt2[cur];
    const float* tsc = tsAll + kt*128;
    floatx4 treg[8];                        // hoisted t-vectors (static idx)
    #pragma unroll
    for (int i = 0; i < 8; ++i)
      treg[i] = *(const floatx4*)&tsc[i*16 + quad*4];
    // one-ahead pipelined kb4 loop (static Sa/Sb names; QK(next) before SOFTPV(cur))
    floatx4 Sa[2][2], Sb[2][2];
    ZERO_S(Sa); QKT(Sa, 0);
    ZERO_S(Sb); QKT(Sb, 1);
    SOFTPV(Sa, 0);
    ZERO_S(Sa); QKT(Sa, 2);
    SOFTPV(Sb, 1);
    ZERO_S(Sb); QKT(Sb, 3);
    SOFTPV(Sa, 2);
    SOFTPV(Sb, 3);
    __syncthreads();
  }
  // l = Lacc[mt][r] (all rows equal, col = lane&15 = q); no cross-lane reduce needed
  #pragma unroll
  for (int mt=0;mt<2;++mt){
    float invl = 1.f / Lacc[mt][0];
    int qrow = qt*128 + w*32 + mt*16 + c;
    size_t rb = ((size_t)b*N_ + qrow)*(size_t)D_;
    #pragma unroll
    for (int nt=0;nt<4;++nt){
      int d0 = h*DH_ + nt*16 + quad*4;     // 4 consecutive d per lane
      uint2v pv;
      pv.x = pk2(O[mt][nt][0]*invl, O[mt][nt][1]*invl);
      pv.y = pk2(O[mt][nt][2]*invl, O[mt][nt][3]*invl);
      *(uint2v*)(o + rb + swz(d0, qrow)) = pv;   // swz keeps 4-short runs intact
    }
  }
}

extern "C" void kernel_launch(void* const* d_in, const int* in_sizes, int n_in,
                              void* d_out, int out_size, void* d_ws, size_t ws_size,
                              hipStream_t stream){
  const float* x      = (const float*)d_in[0];
  const float* coords = (const float*)d_in[1];
  const float* ln1_w  = (const float*)d_in[2];
  const float* ln1_b  = (const float*)d_in[3];
  const float* ln2_w  = (const float*)d_in[4];
  const float* ln2_b  = (const float*)d_in[5];
  const float* Wqkv   = (const float*)d_in[6];
  const float* bqkv   = (const float*)d_in[7];
  const float* Wo     = (const float*)d_in[8];
  const float* bo     = (const float*)d_in[9];
  const float* Wc     = (const float*)d_in[10];
  // d_in[11] = bc: constant over softmax axis -> no effect on output
  const float* W1     = (const float*)d_in[12];
  const float* b1     = (const float*)d_in[13];
  const float* W2     = (const float*)d_in[14];
  const float* b2     = (const float*)d_in[15];
  const float* W3     = (const float*)d_in[16];
  const float* b3     = (const float*)d_in[17];

  // ws layout (peak 40.2 MB), all bf16 raw shorts; swizzled layouts as documented
  char* ws = (char*)d_ws;
  short* Wtqkv = (short*)(ws);                         // [1536][512]
  short* Wto   = (short*)(ws + 1572864);               // [512][512]
  short* Wt1   = (short*)(ws + 2097152);               // [1408][512]
  short* Wt2   = (short*)(ws + 3538944);               // [1408][512]
  short* Wt3   = (short*)(ws + 4980736);               // [512][1408]
  float* tv    = (float*)(ws + 6422528);               // [32][2048]
  short* h     = (short*)(ws + 6684672);               // [8192][512]
  short* qb    = (short*)(ws + 15073280);              // 8 MB
  short* kb    = (short*)(ws + 23461888);              // 8 MB
  short* vbt   = (short*)(ws + 31850496);              // 8 MB  [bh][hd][n]
  short* o     = h;                                    // alias: h dead after qkv
  short* h2    = h;                                    // alias: o dead after wo
  short* ff    = qb;                                   // alias: q/k/v dead after attn
  float* x1    = (float*)d_out;                        // f32 [8192][512] = d_out

  // blocks: [0,3136) weights, [3136,3392) coord proj, [3392,11584) LN1
  convT_all<<<dim3(11584), dim3(256), 0, stream>>>(Wqkv, Wo, W1, W2, W3,
      Wtqkv, Wto, Wt1, Wt2, Wt3, coords, Wc, tv, x, ln1_w, ln1_b, h);
  qkv_gemm<<<dim3(768), dim3(256), 0, stream>>>(h, Wtqkv, bqkv, qb, kb, vbt);
  attn_mfma<<<dim3(512), dim3(256), 0, stream>>>(qb, kb, vbt, tv, o);
  gemm64<<<dim3(512), dim3(256), 0, stream>>>(o, 512, Wto, 512, bo, x, x1);
  ln_kernel<<<dim3(ROWS_), dim3(256), 0, stream>>>(x1, ln2_w, ln2_b, h2);
  gate_gemm<<<dim3(1408), dim3(256), 0, stream>>>(h2, Wt1, Wt2, b1, b2, ff);
  gemm64<<<dim3(512), dim3(256), 0, stream>>>(ff, HIDP, Wt3, HIDP, b3, x1, x1);
}